// Round 1
// baseline (656.519 us; speedup 1.0000x reference)
//
#include <hip/hip_runtime.h>
#include <hip/hip_bf16.h>
#include <math.h>

// Problem constants
#define DIM 128
#define NHEAD 8
#define DHEAD 16
#define HID 512
#define LN_EPS 1e-5f
#define SCORE_SCALE 0.08838834764831845f  // 1/sqrt(128)

// ---------------- CSR build ----------------

__global__ void zero_counts_kernel(int* counts, int n) {
    int i = blockIdx.x * blockDim.x + threadIdx.x;
    if (i < n) counts[i] = 0;
}

__global__ void count_kernel(const int* __restrict__ dst, int* counts, int E) {
    int e = blockIdx.x * blockDim.x + threadIdx.x;
    if (e < E) atomicAdd(&counts[dst[e]], 1);
}

// single-block scan; counts is rewritten in-place as the cursor (== exclusive prefix)
__global__ void scan_kernel(int* counts, int* offsets, int n) {
    __shared__ int sdata[1024];
    int carry = 0;
    for (int base = 0; base < n; base += 1024) {
        int i = base + (int)threadIdx.x;
        int x = (i < n) ? counts[i] : 0;
        sdata[threadIdx.x] = x;
        __syncthreads();
        for (int off = 1; off < 1024; off <<= 1) {
            int t = 0;
            if ((int)threadIdx.x >= off) t = sdata[threadIdx.x - off];
            __syncthreads();
            sdata[threadIdx.x] += t;
            __syncthreads();
        }
        int incl = sdata[threadIdx.x];
        int excl = incl - x;
        if (i < n) {
            offsets[i] = carry + excl;
            counts[i]  = carry + excl;   // cursor for fill
        }
        carry += sdata[1023];
        __syncthreads();
    }
    if (threadIdx.x == 0) offsets[n] = carry;
}

__global__ void fill_kernel(const int* __restrict__ dst, int* cursor, int* eids, int E) {
    int e = blockIdx.x * blockDim.x + threadIdx.x;
    if (e < E) {
        int pos = atomicAdd(&cursor[dst[e]], 1);
        eids[pos] = e;
    }
}

// ---------------- generic tiled fp32 GEMM ----------------
// C[M,N] = A[M,K] @ B[K,N]  (+bias) (+prelu).  M%64==0, N%64==0, K%16==0.
#define BM 64
#define BN 64
#define BK 16

__global__ __launch_bounds__(256) void gemm_kernel(
        const float* __restrict__ A, const float* __restrict__ B, float* __restrict__ C,
        int M, int N, int K,
        const float* __restrict__ bias, const float* __restrict__ prelu) {
    __shared__ float As[BM][BK + 1];
    __shared__ float Bs[BK][BN + 1];
    int tid = threadIdx.x;
    int tx = tid & 15;
    int ty = tid >> 4;
    int arow  = tid >> 2;          // 0..63
    int acol4 = (tid & 3) * 4;     // 0,4,8,12
    int brow  = tid >> 4;          // 0..15
    int bcol4 = (tid & 15) * 4;    // 0..60

    const float* Ab = A + (size_t)(blockIdx.y * BM) * K;
    const float* Bb = B + blockIdx.x * BN;

    float acc[4][4] = {};

    for (int k0 = 0; k0 < K; k0 += BK) {
        float4 a4 = *(const float4*)(Ab + (size_t)arow * K + k0 + acol4);
        As[arow][acol4 + 0] = a4.x; As[arow][acol4 + 1] = a4.y;
        As[arow][acol4 + 2] = a4.z; As[arow][acol4 + 3] = a4.w;
        float4 b4 = *(const float4*)(Bb + (size_t)(k0 + brow) * N + bcol4);
        Bs[brow][bcol4 + 0] = b4.x; Bs[brow][bcol4 + 1] = b4.y;
        Bs[brow][bcol4 + 2] = b4.z; Bs[brow][bcol4 + 3] = b4.w;
        __syncthreads();
#pragma unroll
        for (int kk = 0; kk < BK; ++kk) {
            float a[4], b[4];
#pragma unroll
            for (int i = 0; i < 4; ++i) a[i] = As[ty * 4 + i][kk];
#pragma unroll
            for (int j = 0; j < 4; ++j) b[j] = Bs[kk][tx * 4 + j];
#pragma unroll
            for (int i = 0; i < 4; ++i)
#pragma unroll
                for (int j = 0; j < 4; ++j)
                    acc[i][j] += a[i] * b[j];
        }
        __syncthreads();
    }

    int crow0 = blockIdx.y * BM + ty * 4;
    int ccol0 = blockIdx.x * BN + tx * 4;
    float bi[4] = {0.f, 0.f, 0.f, 0.f};
    float pw[4] = {1.f, 1.f, 1.f, 1.f};
    if (bias) {
#pragma unroll
        for (int j = 0; j < 4; ++j) bi[j] = bias[ccol0 + j];
    }
    if (prelu) {
#pragma unroll
        for (int j = 0; j < 4; ++j) pw[j] = prelu[ccol0 + j];
    }
#pragma unroll
    for (int i = 0; i < 4; ++i) {
        float4 o;
        float v0 = acc[i][0] + bi[0];
        float v1 = acc[i][1] + bi[1];
        float v2 = acc[i][2] + bi[2];
        float v3 = acc[i][3] + bi[3];
        if (prelu) {
            v0 = v0 >= 0.f ? v0 : pw[0] * v0;
            v1 = v1 >= 0.f ? v1 : pw[1] * v1;
            v2 = v2 >= 0.f ? v2 : pw[2] * v2;
            v3 = v3 >= 0.f ? v3 : pw[3] * v3;
        }
        o.x = v0; o.y = v1; o.z = v2; o.w = v3;
        *(float4*)(C + (size_t)(crow0 + i) * N + ccol0) = o;
    }
}

// ---------------- fused attention aggregate + residual + LN1 ----------------
// one wave (64 lanes) per node; 2 features per lane; online softmax over incoming edges
__global__ __launch_bounds__(256) void agg_ln1_kernel(
        const float* __restrict__ q, const float* __restrict__ k, const float* __restrict__ v,
        const float* __restrict__ feat,
        const int* __restrict__ src, const int* __restrict__ eids, const int* __restrict__ offsets,
        const float* __restrict__ g, const float* __restrict__ b,
        float* __restrict__ rst, int n) {
    int wave = blockIdx.x * 4 + (threadIdx.x >> 6);
    int lane = threadIdx.x & 63;
    if (wave >= n) return;
    int node = wave;

    float2 qv = *(const float2*)(q + (size_t)node * DIM + 2 * lane);
    int beg = offsets[node];
    int end = offsets[node + 1];

    float m = -INFINITY;
    float l = 0.f;
    float acc0 = 0.f, acc1 = 0.f;

    for (int idx = beg; idx < end; ++idx) {
        int e = eids[idx];
        int s = src[e];
        float2 kv = *(const float2*)(k + (size_t)s * DIM + 2 * lane);
        float p = kv.x * qv.x + kv.y * qv.y;
        // reduce within 8-lane head group (16 features per head, 2 per lane)
        p += __shfl_xor(p, 1, 8);
        p += __shfl_xor(p, 2, 8);
        p += __shfl_xor(p, 4, 8);
        float sc = p * SCORE_SCALE;
        float mnew = fmaxf(m, sc);
        float f = __expf(m - mnew);    // exp(-inf)=0 on first edge
        float w = __expf(sc - mnew);
        l = l * f + w;
        float2 vv = *(const float2*)(v + (size_t)s * DIM + 2 * lane);
        acc0 = acc0 * f + w * vv.x;
        acc1 = acc1 * f + w * vv.y;
        m = mnew;
    }

    float inv = (l > 0.f) ? 1.f / l : 0.f;
    float2 fv = *(const float2*)(feat + (size_t)node * DIM + 2 * lane);
    float x0 = acc0 * inv + fv.x;
    float x1 = acc1 * inv + fv.y;

    float s1 = x0 + x1;
    float s2 = x0 * x0 + x1 * x1;
#pragma unroll
    for (int off = 1; off < 64; off <<= 1) {
        s1 += __shfl_xor(s1, off, 64);
        s2 += __shfl_xor(s2, off, 64);
    }
    float mean = s1 * (1.f / DIM);
    float var = s2 * (1.f / DIM) - mean * mean;
    float rinv = rsqrtf(var + LN_EPS);
    float g0 = g[2 * lane], g1 = g[2 * lane + 1];
    float b0 = b[2 * lane], b1 = b[2 * lane + 1];
    float2 o;
    o.x = (x0 - mean) * rinv * g0 + b0;
    o.y = (x1 - mean) * rinv * g1 + b1;
    *(float2*)(rst + (size_t)node * DIM + 2 * lane) = o;
}

// ---------------- final residual + LN2 ----------------
__global__ __launch_bounds__(256) void ln2_kernel(
        const float* __restrict__ ffn, const float* __restrict__ rst,
        const float* __restrict__ g, const float* __restrict__ b,
        float* __restrict__ out, int n) {
    int wave = blockIdx.x * 4 + (threadIdx.x >> 6);
    int lane = threadIdx.x & 63;
    if (wave >= n) return;
    int node = wave;
    float2 a = *(const float2*)(ffn + (size_t)node * DIM + 2 * lane);
    float2 r = *(const float2*)(rst + (size_t)node * DIM + 2 * lane);
    float x0 = a.x + r.x;
    float x1 = a.y + r.y;
    float s1 = x0 + x1;
    float s2 = x0 * x0 + x1 * x1;
#pragma unroll
    for (int off = 1; off < 64; off <<= 1) {
        s1 += __shfl_xor(s1, off, 64);
        s2 += __shfl_xor(s2, off, 64);
    }
    float mean = s1 * (1.f / DIM);
    float var = s2 * (1.f / DIM) - mean * mean;
    float rinv = rsqrtf(var + LN_EPS);
    float g0 = g[2 * lane], g1 = g[2 * lane + 1];
    float b0 = b[2 * lane], b1 = b[2 * lane + 1];
    float2 o;
    o.x = (x0 - mean) * rinv * g0 + b0;
    o.y = (x1 - mean) * rinv * g1 + b1;
    *(float2*)(out + (size_t)node * DIM + 2 * lane) = o;
}

// ---------------- launch ----------------

extern "C" void kernel_launch(void* const* d_in, const int* in_sizes, int n_in,
                              void* d_out, int out_size, void* d_ws, size_t ws_size,
                              hipStream_t stream) {
    const float* feat   = (const float*)d_in[0];
    const int*   src    = (const int*)d_in[1];
    const int*   dst    = (const int*)d_in[2];
    const float* Wq     = (const float*)d_in[3];
    const float* Wk     = (const float*)d_in[4];
    const float* Wv     = (const float*)d_in[5];
    const float* ln1_g  = (const float*)d_in[6];
    const float* ln1_b  = (const float*)d_in[7];
    const float* ln2_g  = (const float*)d_in[8];
    const float* ln2_b  = (const float*)d_in[9];
    const float* W1     = (const float*)d_in[10];
    const float* b1     = (const float*)d_in[11];
    const float* prelu  = (const float*)d_in[12];
    const float* W2     = (const float*)d_in[13];
    const float* b2     = (const float*)d_in[14];
    float* out = (float*)d_out;

    const int Nn = in_sizes[0] / DIM;   // 40000
    const int E  = in_sizes[1];         // 640000

    // workspace layout (floats)
    float* ws = (float*)d_ws;
    float* rst  = ws;                                  // Nn*128
    float* big  = rst + (size_t)Nn * DIM;              // max(3*Nn*128 qkv, Nn*512 hid)
    float* qb   = big;
    float* kb   = big + (size_t)Nn * DIM;
    float* vb   = big + (size_t)2 * Nn * DIM;
    float* hbuf = big;                                 // Nn*512 (after aggregation)
    float* ffn  = big + (size_t)Nn * HID;              // Nn*128
    int*   counts  = (int*)(ffn + (size_t)Nn * DIM);   // Nn (becomes cursor)
    int*   offsets = counts + Nn;                      // Nn+1
    int*   eids    = offsets + Nn + 1;                 // E

    // 1. CSR build
    zero_counts_kernel<<<(Nn + 255) / 256, 256, 0, stream>>>(counts, Nn);
    count_kernel<<<(E + 255) / 256, 256, 0, stream>>>(dst, counts, E);
    scan_kernel<<<1, 1024, 0, stream>>>(counts, offsets, Nn);
    fill_kernel<<<(E + 255) / 256, 256, 0, stream>>>(dst, counts, eids, E);

    // 2. q,k,v projections: [Nn,128] @ [128,128]
    dim3 gqkv(DIM / BN, Nn / BM);
    gemm_kernel<<<gqkv, 256, 0, stream>>>(feat, Wq, qb, Nn, DIM, DIM, nullptr, nullptr);
    gemm_kernel<<<gqkv, 256, 0, stream>>>(feat, Wk, kb, Nn, DIM, DIM, nullptr, nullptr);
    gemm_kernel<<<gqkv, 256, 0, stream>>>(feat, Wv, vb, Nn, DIM, DIM, nullptr, nullptr);

    // 3. fused attention + residual + LN1 -> rst
    agg_ln1_kernel<<<(Nn + 3) / 4, 256, 0, stream>>>(qb, kb, vb, feat, src, eids, offsets,
                                                     ln1_g, ln1_b, rst, Nn);

    // 4. FFN1: rst @ W1 + b1, PReLU -> hbuf  (overwrites q/k/v region — they are dead)
    dim3 g1(HID / BN, Nn / BM);
    gemm_kernel<<<g1, 256, 0, stream>>>(rst, W1, hbuf, Nn, HID, DIM, b1, prelu);

    // 5. FFN2: hbuf @ W2 + b2 -> ffn
    dim3 g2(DIM / BN, Nn / BM);
    gemm_kernel<<<g2, 256, 0, stream>>>(hbuf, W2, ffn, Nn, DIM, HID, b2, nullptr);

    // 6. LN2(rst + ffn) -> out
    ln2_kernel<<<(Nn + 3) / 4, 256, 0, stream>>>(ffn, rst, ln2_g, ln2_b, out, Nn);
}

// Round 2
// 334.348 us; speedup vs baseline: 1.9636x; 1.9636x over previous
//
#include <hip/hip_runtime.h>
#include <hip/hip_bf16.h>
#include <math.h>

#define DIM 128
#define NHEAD 8
#define DHEAD 16
#define HID 512
#define LN_EPS 1e-5f
#define SCORE_SCALE 0.08838834764831845f  // 1/sqrt(128)

typedef __bf16 bf16x8 __attribute__((ext_vector_type(8)));
typedef float f32x4 __attribute__((ext_vector_type(4)));

__device__ inline float bf2f(unsigned int bits16) {
    return __uint_as_float(bits16 << 16);
}
__device__ inline unsigned short f2bf(float f) {
    unsigned int u = __float_as_uint(f);
    unsigned int r = u + 0x7fff + ((u >> 16) & 1);   // RNE (non-NaN inputs)
    return (unsigned short)(r >> 16);
}

// ---------------- CSR build ----------------

__global__ void zero_counts_kernel(int* counts, int n) {
    int i = blockIdx.x * blockDim.x + threadIdx.x;
    if (i < n) counts[i] = 0;
}

__global__ void count_kernel(const int* __restrict__ dst, int* counts, int E) {
    int e = blockIdx.x * blockDim.x + threadIdx.x;
    if (e < E) atomicAdd(&counts[dst[e]], 1);
}

// single-block shfl-based scan; counts rewritten in-place as cursor (exclusive prefix)
__global__ __launch_bounds__(1024) void scan_kernel(int* counts, int* offsets, int n) {
    __shared__ int wsum[16];
    __shared__ int carry_s;
    int lane = threadIdx.x & 63;
    int wid = threadIdx.x >> 6;
    if (threadIdx.x == 0) carry_s = 0;
    __syncthreads();
    for (int base = 0; base < n; base += 1024) {
        int i = base + (int)threadIdx.x;
        int x = (i < n) ? counts[i] : 0;
        int s = x;
#pragma unroll
        for (int off = 1; off < 64; off <<= 1) {
            int t = __shfl_up(s, off, 64);
            if (lane >= off) s += t;
        }
        if (lane == 63) wsum[wid] = s;
        __syncthreads();
        if ((int)threadIdx.x < 16) {
            int t = wsum[threadIdx.x];
#pragma unroll
            for (int off = 1; off < 16; off <<= 1) {
                int u = __shfl_up(t, off, 64);
                if ((int)threadIdx.x >= off) t += u;
            }
            wsum[threadIdx.x] = t;
        }
        __syncthreads();
        int waveoff = (wid == 0) ? 0 : wsum[wid - 1];
        int incl = s + waveoff;
        int excl = incl - x;
        int carry = carry_s;
        if (i < n) { offsets[i] = carry + excl; counts[i] = carry + excl; }
        __syncthreads();
        if (threadIdx.x == 1023) carry_s = carry + incl;
        __syncthreads();
    }
    if (threadIdx.x == 0) offsets[n] = carry_s;
}

// stores src node id sorted by dst (no eids indirection needed later)
__global__ void fill_kernel(const int* __restrict__ dst, const int* __restrict__ src,
                            int* cursor, int* srcs, int E) {
    int e = blockIdx.x * blockDim.x + threadIdx.x;
    if (e < E) {
        int pos = atomicAdd(&cursor[dst[e]], 1);
        srcs[pos] = src[e];
    }
}

// ---------------- converts ----------------

__global__ void cvt_bf16_kernel(const float* __restrict__ in, unsigned short* __restrict__ out, int n4) {
    int i = blockIdx.x * blockDim.x + threadIdx.x;
    if (i < n4) {
        float4 v = *(const float4*)(in + (size_t)i * 4);
        ushort4 o;
        o.x = f2bf(v.x); o.y = f2bf(v.y); o.z = f2bf(v.z); o.w = f2bf(v.w);
        *(ushort4*)(out + (size_t)i * 4) = o;
    }
}

// in: [R][C] fp32 -> out: [C][R] bf16
__global__ void transpose_cvt_kernel(const float* __restrict__ in, unsigned short* __restrict__ out,
                                     int R, int C) {
    int i = blockIdx.x * blockDim.x + threadIdx.x;
    if (i < R * C) {
        int c = i / R;
        int r = i - c * R;
        out[(size_t)c * R + r] = f2bf(in[(size_t)r * C + c]);
    }
}

// ---------------- bf16 MFMA GEMM ----------------
// C[M,N] = A[M,K] @ B[K,N], where Bt is B^T stored [N][K] bf16 row-major.
// BM=BN=64, BK=32; 4 waves, each computes a 32x32 sub-tile via 2x2 mfma_f32_16x16x32_bf16.
#define GBM 64
#define GBN 64
#define GBK 32
#define LDK (GBK + 8)

template <bool OUT_BF16>
__global__ __launch_bounds__(256) void mfma_gemm(
        const unsigned short* __restrict__ A, const unsigned short* __restrict__ Bt,
        void* __restrict__ C, int M, int N, int K,
        const float* __restrict__ bias, const float* __restrict__ prelu) {
    __shared__ unsigned short As[GBM][LDK];
    __shared__ unsigned short Bs[GBN][LDK];
    int tid = threadIdx.x;
    int wave = tid >> 6, lane = tid & 63;
    int wr = wave >> 1, wc = wave & 1;    // 32x32 wave tile at (wr*32, wc*32)
    int lrow = lane & 15, kq = lane >> 4; // fragment row/col + k-quad

    int m0 = blockIdx.y * GBM;
    int n0 = blockIdx.x * GBN;

    int srow = tid >> 2;        // 0..63
    int scol = (tid & 3) * 8;   // 0,8,16,24

    f32x4 acc[2][2] = {};

    for (int k0 = 0; k0 < K; k0 += GBK) {
        float4 av = *(const float4*)(A + (size_t)(m0 + srow) * K + k0 + scol);
        float4 bv = *(const float4*)(Bt + (size_t)(n0 + srow) * K + k0 + scol);
        *(float4*)(&As[srow][scol]) = av;
        *(float4*)(&Bs[srow][scol]) = bv;
        __syncthreads();
        bf16x8 af0 = *(const bf16x8*)(&As[wr * 32 + lrow][kq * 8]);
        bf16x8 af1 = *(const bf16x8*)(&As[wr * 32 + 16 + lrow][kq * 8]);
        bf16x8 bf0 = *(const bf16x8*)(&Bs[wc * 32 + lrow][kq * 8]);
        bf16x8 bf1 = *(const bf16x8*)(&Bs[wc * 32 + 16 + lrow][kq * 8]);
        acc[0][0] = __builtin_amdgcn_mfma_f32_16x16x32_bf16(af0, bf0, acc[0][0], 0, 0, 0);
        acc[0][1] = __builtin_amdgcn_mfma_f32_16x16x32_bf16(af0, bf1, acc[0][1], 0, 0, 0);
        acc[1][0] = __builtin_amdgcn_mfma_f32_16x16x32_bf16(af1, bf0, acc[1][0], 0, 0, 0);
        acc[1][1] = __builtin_amdgcn_mfma_f32_16x16x32_bf16(af1, bf1, acc[1][1], 0, 0, 0);
        __syncthreads();
    }

    // epilogue: C/D layout col=lane&15, row=(lane>>4)*4+r
#pragma unroll
    for (int ni = 0; ni < 2; ++ni) {
        int col = n0 + wc * 32 + ni * 16 + lrow;
        float bi = bias ? bias[col] : 0.f;
        float pw = prelu ? prelu[col] : 1.f;
#pragma unroll
        for (int mi = 0; mi < 2; ++mi) {
#pragma unroll
            for (int r = 0; r < 4; ++r) {
                int row = m0 + wr * 32 + mi * 16 + kq * 4 + r;
                float v = acc[mi][ni][r] + bi;
                if (prelu) v = v >= 0.f ? v : pw * v;
                if (OUT_BF16)
                    ((unsigned short*)C)[(size_t)row * N + col] = f2bf(v);
                else
                    ((float*)C)[(size_t)row * N + col] = v;
            }
        }
    }
}

// ---------------- fused attention aggregate + residual + LN1 ----------------
// one wave per node, 2 features/lane; qkv is bf16 [N][384] (q|k|v); 4-edge chunks for MLP
__global__ __launch_bounds__(256) void agg_ln1_kernel(
        const unsigned short* __restrict__ qkv,
        const float* __restrict__ feat,
        const int* __restrict__ srcs, const int* __restrict__ offsets,
        const float* __restrict__ g, const float* __restrict__ b,
        float* __restrict__ rstf, unsigned short* __restrict__ rstb, int n) {
    int node = blockIdx.x * 4 + (threadIdx.x >> 6);
    int lane = threadIdx.x & 63;
    if (node >= n) return;

    const unsigned int* base = (const unsigned int*)qkv;  // row stride = 192 words
    unsigned int qw = base[(size_t)node * 192 + lane];
    float q0 = bf2f(qw & 0xffffu), q1 = bf2f(qw >> 16);

    int beg = offsets[node], end = offsets[node + 1];
    float m = -INFINITY, l = 0.f, a0 = 0.f, a1 = 0.f;

    for (int idx = beg; idx < end; idx += 4) {
        int cnt = end - idx;
        int s0 = srcs[idx];
        int s1 = cnt > 1 ? srcs[idx + 1] : s0;
        int s2 = cnt > 2 ? srcs[idx + 2] : s0;
        int s3 = cnt > 3 ? srcs[idx + 3] : s0;
        unsigned int kw0 = base[(size_t)s0 * 192 + 64 + lane];
        unsigned int kw1 = base[(size_t)s1 * 192 + 64 + lane];
        unsigned int kw2 = base[(size_t)s2 * 192 + 64 + lane];
        unsigned int kw3 = base[(size_t)s3 * 192 + 64 + lane];
        unsigned int vw0 = base[(size_t)s0 * 192 + 128 + lane];
        unsigned int vw1 = base[(size_t)s1 * 192 + 128 + lane];
        unsigned int vw2 = base[(size_t)s2 * 192 + 128 + lane];
        unsigned int vw3 = base[(size_t)s3 * 192 + 128 + lane];

        float p0 = bf2f(kw0 & 0xffffu) * q0 + bf2f(kw0 >> 16) * q1;
        float p1 = bf2f(kw1 & 0xffffu) * q0 + bf2f(kw1 >> 16) * q1;
        float p2 = bf2f(kw2 & 0xffffu) * q0 + bf2f(kw2 >> 16) * q1;
        float p3 = bf2f(kw3 & 0xffffu) * q0 + bf2f(kw3 >> 16) * q1;
#pragma unroll
        for (int off = 1; off < 8; off <<= 1) {
            p0 += __shfl_xor(p0, off, 8);
            p1 += __shfl_xor(p1, off, 8);
            p2 += __shfl_xor(p2, off, 8);
            p3 += __shfl_xor(p3, off, 8);
        }
        {
            float sc = p0 * SCORE_SCALE;
            float mn = fmaxf(m, sc);
            float f = __expf(m - mn), w = __expf(sc - mn);
            l = l * f + w;
            a0 = a0 * f + w * bf2f(vw0 & 0xffffu);
            a1 = a1 * f + w * bf2f(vw0 >> 16);
            m = mn;
        }
        if (cnt > 1) {
            float sc = p1 * SCORE_SCALE;
            float mn = fmaxf(m, sc);
            float f = __expf(m - mn), w = __expf(sc - mn);
            l = l * f + w;
            a0 = a0 * f + w * bf2f(vw1 & 0xffffu);
            a1 = a1 * f + w * bf2f(vw1 >> 16);
            m = mn;
        }
        if (cnt > 2) {
            float sc = p2 * SCORE_SCALE;
            float mn = fmaxf(m, sc);
            float f = __expf(m - mn), w = __expf(sc - mn);
            l = l * f + w;
            a0 = a0 * f + w * bf2f(vw2 & 0xffffu);
            a1 = a1 * f + w * bf2f(vw2 >> 16);
            m = mn;
        }
        if (cnt > 3) {
            float sc = p3 * SCORE_SCALE;
            float mn = fmaxf(m, sc);
            float f = __expf(m - mn), w = __expf(sc - mn);
            l = l * f + w;
            a0 = a0 * f + w * bf2f(vw3 & 0xffffu);
            a1 = a1 * f + w * bf2f(vw3 >> 16);
            m = mn;
        }
    }

    float inv = (l > 0.f) ? 1.f / l : 0.f;
    float2 fv = *(const float2*)(feat + (size_t)node * DIM + 2 * lane);
    float x0 = a0 * inv + fv.x;
    float x1 = a1 * inv + fv.y;

    float s1 = x0 + x1;
    float s2 = x0 * x0 + x1 * x1;
#pragma unroll
    for (int off = 1; off < 64; off <<= 1) {
        s1 += __shfl_xor(s1, off, 64);
        s2 += __shfl_xor(s2, off, 64);
    }
    float mean = s1 * (1.f / DIM);
    float var = s2 * (1.f / DIM) - mean * mean;
    float rinv = rsqrtf(var + LN_EPS);
    float g0 = g[2 * lane], g1 = g[2 * lane + 1];
    float b0 = b[2 * lane], b1 = b[2 * lane + 1];
    float o0 = (x0 - mean) * rinv * g0 + b0;
    float o1 = (x1 - mean) * rinv * g1 + b1;
    *(float2*)(rstf + (size_t)node * DIM + 2 * lane) = make_float2(o0, o1);
    unsigned int packed = (unsigned int)f2bf(o0) | ((unsigned int)f2bf(o1) << 16);
    ((unsigned int*)rstb)[(size_t)node * 64 + lane] = packed;
}

// ---------------- final residual + LN2 ----------------
__global__ __launch_bounds__(256) void ln2_kernel(
        const float* __restrict__ ffn, const float* __restrict__ rst,
        const float* __restrict__ g, const float* __restrict__ b,
        float* __restrict__ out, int n) {
    int node = blockIdx.x * 4 + (threadIdx.x >> 6);
    int lane = threadIdx.x & 63;
    if (node >= n) return;
    float2 a = *(const float2*)(ffn + (size_t)node * DIM + 2 * lane);
    float2 r = *(const float2*)(rst + (size_t)node * DIM + 2 * lane);
    float x0 = a.x + r.x;
    float x1 = a.y + r.y;
    float s1 = x0 + x1;
    float s2 = x0 * x0 + x1 * x1;
#pragma unroll
    for (int off = 1; off < 64; off <<= 1) {
        s1 += __shfl_xor(s1, off, 64);
        s2 += __shfl_xor(s2, off, 64);
    }
    float mean = s1 * (1.f / DIM);
    float var = s2 * (1.f / DIM) - mean * mean;
    float rinv = rsqrtf(var + LN_EPS);
    float g0 = g[2 * lane], g1 = g[2 * lane + 1];
    float b0 = b[2 * lane], b1 = b[2 * lane + 1];
    float2 o;
    o.x = (x0 - mean) * rinv * g0 + b0;
    o.y = (x1 - mean) * rinv * g1 + b1;
    *(float2*)(out + (size_t)node * DIM + 2 * lane) = o;
}

// ---------------- launch ----------------

extern "C" void kernel_launch(void* const* d_in, const int* in_sizes, int n_in,
                              void* d_out, int out_size, void* d_ws, size_t ws_size,
                              hipStream_t stream) {
    const float* feat   = (const float*)d_in[0];
    const int*   src    = (const int*)d_in[1];
    const int*   dst    = (const int*)d_in[2];
    const float* Wq     = (const float*)d_in[3];
    const float* Wk     = (const float*)d_in[4];
    const float* Wv     = (const float*)d_in[5];
    const float* ln1_g  = (const float*)d_in[6];
    const float* ln1_b  = (const float*)d_in[7];
    const float* ln2_g  = (const float*)d_in[8];
    const float* ln2_b  = (const float*)d_in[9];
    const float* W1     = (const float*)d_in[10];
    const float* b1     = (const float*)d_in[11];
    const float* prelu  = (const float*)d_in[12];
    const float* W2     = (const float*)d_in[13];
    const float* b2     = (const float*)d_in[14];
    float* out = (float*)d_out;

    const int Nn = in_sizes[0] / DIM;   // 40000
    const int E  = in_sizes[1];         // 640000

    // workspace layout
    char* w = (char*)d_ws;
    float* rstf = (float*)w;             w += (size_t)Nn * DIM * 4;
    unsigned short* rstb = (unsigned short*)w;  w += (size_t)Nn * DIM * 2;
    unsigned short* featb = (unsigned short*)w; w += (size_t)Nn * DIM * 2;
    unsigned short* qkv = (unsigned short*)w;   // union with hid
    unsigned short* hid = (unsigned short*)w;   w += (size_t)Nn * HID * 2;
    float* ffn = (float*)w;              w += (size_t)Nn * DIM * 4;
    unsigned short* Wqkv_t = (unsigned short*)w; w += 3 * DIM * DIM * 2;
    unsigned short* W1_t = (unsigned short*)w;   w += HID * DIM * 2;
    unsigned short* W2_t = (unsigned short*)w;   w += DIM * HID * 2;
    int* counts  = (int*)w;  w += (size_t)Nn * 4;
    int* offsets = (int*)w;  w += (size_t)(Nn + 1) * 4;
    int* srcs    = (int*)w;

    // 1. CSR build (srcs sorted by dst)
    zero_counts_kernel<<<(Nn + 255) / 256, 256, 0, stream>>>(counts, Nn);
    count_kernel<<<(E + 255) / 256, 256, 0, stream>>>(dst, counts, E);
    scan_kernel<<<1, 1024, 0, stream>>>(counts, offsets, Nn);
    fill_kernel<<<(E + 255) / 256, 256, 0, stream>>>(dst, src, counts, srcs, E);

    // 2. converts: feat -> bf16; weights -> transposed bf16
    cvt_bf16_kernel<<<((Nn * DIM / 4) + 255) / 256, 256, 0, stream>>>(feat, featb, Nn * DIM / 4);
    transpose_cvt_kernel<<<(DIM * DIM + 255) / 256, 256, 0, stream>>>(Wq, Wqkv_t, DIM, DIM);
    transpose_cvt_kernel<<<(DIM * DIM + 255) / 256, 256, 0, stream>>>(Wk, Wqkv_t + DIM * DIM, DIM, DIM);
    transpose_cvt_kernel<<<(DIM * DIM + 255) / 256, 256, 0, stream>>>(Wv, Wqkv_t + 2 * DIM * DIM, DIM, DIM);
    transpose_cvt_kernel<<<(DIM * HID + 255) / 256, 256, 0, stream>>>(W1, W1_t, DIM, HID);
    transpose_cvt_kernel<<<(HID * DIM + 255) / 256, 256, 0, stream>>>(W2, W2_t, HID, DIM);

    // 3. fused qkv projection: [Nn,128] @ [128,384] -> bf16 qkv
    {
        dim3 grid(3 * DIM / GBN, Nn / GBM);
        mfma_gemm<true><<<grid, 256, 0, stream>>>(featb, Wqkv_t, qkv, Nn, 3 * DIM, DIM,
                                                  nullptr, nullptr);
    }

    // 4. fused attention + residual + LN1 -> rstf (fp32) + rstb (bf16)
    agg_ln1_kernel<<<(Nn + 3) / 4, 256, 0, stream>>>(qkv, feat, srcs, offsets,
                                                     ln1_g, ln1_b, rstf, rstb, Nn);

    // 5. FFN1: rstb @ W1 + b1, PReLU -> hid (bf16; overwrites dead qkv region)
    {
        dim3 grid(HID / GBN, Nn / GBM);
        mfma_gemm<true><<<grid, 256, 0, stream>>>(rstb, W1_t, hid, Nn, HID, DIM, b1, prelu);
    }

    // 6. FFN2: hid @ W2 + b2 -> ffn (fp32)
    {
        dim3 grid(DIM / GBN, Nn / GBM);
        mfma_gemm<false><<<grid, 256, 0, stream>>>(hid, W2_t, ffn, Nn, DIM, HID, b2, nullptr);
    }

    // 7. LN2(rstf + ffn) -> out
    ln2_kernel<<<(Nn + 3) / 4, 256, 0, stream>>>(ffn, rstf, ln2_g, ln2_b, out, Nn);
}

// Round 3
// 330.352 us; speedup vs baseline: 1.9873x; 1.0121x over previous
//
#include <hip/hip_runtime.h>
#include <hip/hip_bf16.h>
#include <math.h>

#define DIM 128
#define NHEAD 8
#define DHEAD 16
#define HID 512
#define LN_EPS 1e-5f
#define SCORE_SCALE 0.08838834764831845f  // 1/sqrt(128)

typedef __bf16 bf16x8 __attribute__((ext_vector_type(8)));
typedef float f32x4 __attribute__((ext_vector_type(4)));

__device__ inline float bf2f(unsigned int bits16) {
    return __uint_as_float(bits16 << 16);
}
__device__ inline unsigned short f2bf(float f) {
    unsigned int u = __float_as_uint(f);
    unsigned int r = u + 0x7fff + ((u >> 16) & 1);   // RNE (non-NaN inputs)
    return (unsigned short)(r >> 16);
}

// async global->LDS, 16 bytes per lane; lds dest must be wave-uniform base + lane*16
__device__ inline void gload_lds16(const void* g, void* l) {
    __builtin_amdgcn_global_load_lds(
        (const __attribute__((address_space(1))) unsigned int*)g,
        (__attribute__((address_space(3))) unsigned int*)l, 16, 0, 0);
}

// ---------------- CSR build ----------------

__global__ void zero_counts_kernel(int* counts, int n) {
    int i = blockIdx.x * blockDim.x + threadIdx.x;
    if (i < n) counts[i] = 0;
}

__global__ void count_kernel(const int* __restrict__ dst, int* counts, int E) {
    int e = blockIdx.x * blockDim.x + threadIdx.x;
    if (e < E) atomicAdd(&counts[dst[e]], 1);
}

// single-block shfl-based scan; counts rewritten in-place as cursor (exclusive prefix)
__global__ __launch_bounds__(1024) void scan_kernel(int* counts, int* offsets, int n) {
    __shared__ int wsum[16];
    __shared__ int carry_s;
    int lane = threadIdx.x & 63;
    int wid = threadIdx.x >> 6;
    if (threadIdx.x == 0) carry_s = 0;
    __syncthreads();
    for (int base = 0; base < n; base += 1024) {
        int i = base + (int)threadIdx.x;
        int x = (i < n) ? counts[i] : 0;
        int s = x;
#pragma unroll
        for (int off = 1; off < 64; off <<= 1) {
            int t = __shfl_up(s, off, 64);
            if (lane >= off) s += t;
        }
        if (lane == 63) wsum[wid] = s;
        __syncthreads();
        if ((int)threadIdx.x < 16) {
            int t = wsum[threadIdx.x];
#pragma unroll
            for (int off = 1; off < 16; off <<= 1) {
                int u = __shfl_up(t, off, 64);
                if ((int)threadIdx.x >= off) t += u;
            }
            wsum[threadIdx.x] = t;
        }
        __syncthreads();
        int waveoff = (wid == 0) ? 0 : wsum[wid - 1];
        int incl = s + waveoff;
        int excl = incl - x;
        int carry = carry_s;
        if (i < n) { offsets[i] = carry + excl; counts[i] = carry + excl; }
        __syncthreads();
        if (threadIdx.x == 1023) carry_s = carry + incl;
        __syncthreads();
    }
    if (threadIdx.x == 0) offsets[n] = carry_s;
}

// stores src node id sorted by dst
__global__ void fill_kernel(const int* __restrict__ dst, const int* __restrict__ src,
                            int* cursor, int* srcs, int E) {
    int e = blockIdx.x * blockDim.x + threadIdx.x;
    if (e < E) {
        int pos = atomicAdd(&cursor[dst[e]], 1);
        srcs[pos] = src[e];
    }
}

// ---------------- converts ----------------

__global__ void cvt_bf16_kernel(const float* __restrict__ in, unsigned short* __restrict__ out, int n4) {
    int i = blockIdx.x * blockDim.x + threadIdx.x;
    if (i < n4) {
        float4 v = *(const float4*)(in + (size_t)i * 4);
        ushort4 o;
        o.x = f2bf(v.x); o.y = f2bf(v.y); o.z = f2bf(v.z); o.w = f2bf(v.w);
        *(ushort4*)(out + (size_t)i * 4) = o;
    }
}

// in: [R][C] fp32 -> out: [C][R] bf16
__global__ void transpose_cvt_kernel(const float* __restrict__ in, unsigned short* __restrict__ out,
                                     int R, int C) {
    int i = blockIdx.x * blockDim.x + threadIdx.x;
    if (i < R * C) {
        int c = i / R;
        int r = i - c * R;
        out[(size_t)c * R + r] = f2bf(in[(size_t)r * C + c]);
    }
}

// ---------------- bf16 MFMA GEMM, m97-style 128x128 tile ----------------
// C[M,N] = A[M,K] @ B[K,N], Bt = B^T stored [N][K] bf16.
// 256 threads = 4 waves in 2x2; each wave computes 64x64 via 4x4 mfma_f32_16x16x32_bf16.
// Staging via global_load_lds width=16. M must be a multiple of 128 (padded buffers,
// garbage rows beyond the real M are computed and stored — all buffers are padded).
template <bool OUT_BF16>
__global__ __launch_bounds__(256) void mfma_gemm128(
        const unsigned short* __restrict__ A, const unsigned short* __restrict__ Bt,
        void* __restrict__ C, int N, int K,
        const float* __restrict__ bias, const float* __restrict__ prelu) {
    __shared__ unsigned short As[128 * 32];   // row-major [128][32], rows 64B, NO pad
    __shared__ unsigned short Bs[128 * 32];
    int t = threadIdx.x;
    int wave = t >> 6, lane = t & 63;
    int wr = wave >> 1, wc = wave & 1;
    int lrow = lane & 15, kq = lane >> 4;

    int m0 = blockIdx.y * 128;
    int n0 = blockIdx.x * 128;

    int srow = t >> 2;          // 0..63
    int scol8 = (t & 3) * 8;    // bf16 col offset: 0,8,16,24

    f32x4 acc[4][4] = {};

    for (int k0 = 0; k0 < K; k0 += 32) {
        // stage A[128][32] and Bt[128][32] tiles: 2 halves x 16B per thread each
        gload_lds16(A + (size_t)(m0 + srow) * K + k0 + scol8,      As + t * 8);
        gload_lds16(A + (size_t)(m0 + 64 + srow) * K + k0 + scol8, As + 2048 + t * 8);
        gload_lds16(Bt + (size_t)(n0 + srow) * K + k0 + scol8,      Bs + t * 8);
        gload_lds16(Bt + (size_t)(n0 + 64 + srow) * K + k0 + scol8, Bs + 2048 + t * 8);
        __syncthreads();

        bf16x8 af[4], bfr[4];
#pragma unroll
        for (int mi = 0; mi < 4; ++mi)
            af[mi] = *(const bf16x8*)(&As[(wr * 64 + mi * 16 + lrow) * 32 + kq * 8]);
#pragma unroll
        for (int ni = 0; ni < 4; ++ni)
            bfr[ni] = *(const bf16x8*)(&Bs[(wc * 64 + ni * 16 + lrow) * 32 + kq * 8]);
#pragma unroll
        for (int mi = 0; mi < 4; ++mi)
#pragma unroll
            for (int ni = 0; ni < 4; ++ni)
                acc[mi][ni] = __builtin_amdgcn_mfma_f32_16x16x32_bf16(af[mi], bfr[ni], acc[mi][ni], 0, 0, 0);
        __syncthreads();
    }

    // epilogue: C/D layout col=lane&15, row=(lane>>4)*4+r
#pragma unroll
    for (int ni = 0; ni < 4; ++ni) {
        int col = n0 + wc * 64 + ni * 16 + lrow;
        float bi = bias ? bias[col] : 0.f;
        float pw = prelu ? prelu[col] : 1.f;
#pragma unroll
        for (int mi = 0; mi < 4; ++mi) {
#pragma unroll
            for (int r = 0; r < 4; ++r) {
                int row = m0 + wr * 64 + mi * 16 + kq * 4 + r;
                float v = acc[mi][ni][r] + bi;
                if (prelu) v = v >= 0.f ? v : pw * v;
                if (OUT_BF16)
                    ((unsigned short*)C)[(size_t)row * N + col] = f2bf(v);
                else
                    ((float*)C)[(size_t)row * N + col] = v;
            }
        }
    }
}

// ---------------- fused attention aggregate + residual + LN1 ----------------
// one wave per node, 2 features/lane; qkv bf16 [N][384]; 8-edge chunks, chunk-level rescale
__global__ __launch_bounds__(256) void agg_ln1_kernel(
        const unsigned short* __restrict__ qkv,
        const float* __restrict__ feat,
        const int* __restrict__ srcs, const int* __restrict__ offsets,
        const float* __restrict__ g, const float* __restrict__ b,
        float* __restrict__ rstf, unsigned short* __restrict__ rstb, int n) {
    int node = blockIdx.x * 4 + (threadIdx.x >> 6);
    int lane = threadIdx.x & 63;
    if (node >= n) return;

    const unsigned int* base = (const unsigned int*)qkv;  // row stride = 192 words
    unsigned int qw = base[(size_t)node * 192 + lane];
    float q0 = bf2f(qw & 0xffffu), q1 = bf2f(qw >> 16);

    int beg = offsets[node], end = offsets[node + 1];
    float m = -INFINITY, l = 0.f, a0 = 0.f, a1 = 0.f;

    int idx = beg;
    for (; idx + 8 <= end; idx += 8) {
        int s[8];
#pragma unroll
        for (int i = 0; i < 8; ++i) s[i] = srcs[idx + i];
        unsigned int kw[8], vw[8];
#pragma unroll
        for (int i = 0; i < 8; ++i) kw[i] = base[(size_t)s[i] * 192 + 64 + lane];
#pragma unroll
        for (int i = 0; i < 8; ++i) vw[i] = base[(size_t)s[i] * 192 + 128 + lane];
        float sc[8];
#pragma unroll
        for (int i = 0; i < 8; ++i) {
            float p = bf2f(kw[i] & 0xffffu) * q0 + bf2f(kw[i] >> 16) * q1;
            p += __shfl_xor(p, 1, 8);
            p += __shfl_xor(p, 2, 8);
            p += __shfl_xor(p, 4, 8);
            sc[i] = p * SCORE_SCALE;
        }
        float mn = m;
#pragma unroll
        for (int i = 0; i < 8; ++i) mn = fmaxf(mn, sc[i]);
        float f = __expf(m - mn);
        float wsum = 0.f, d0 = 0.f, d1 = 0.f;
#pragma unroll
        for (int i = 0; i < 8; ++i) {
            float w = __expf(sc[i] - mn);
            wsum += w;
            d0 += w * bf2f(vw[i] & 0xffffu);
            d1 += w * bf2f(vw[i] >> 16);
        }
        l = l * f + wsum;
        a0 = a0 * f + d0;
        a1 = a1 * f + d1;
        m = mn;
    }
    for (; idx < end; ++idx) {
        int s = srcs[idx];
        unsigned int kw = base[(size_t)s * 192 + 64 + lane];
        unsigned int vw = base[(size_t)s * 192 + 128 + lane];
        float p = bf2f(kw & 0xffffu) * q0 + bf2f(kw >> 16) * q1;
        p += __shfl_xor(p, 1, 8);
        p += __shfl_xor(p, 2, 8);
        p += __shfl_xor(p, 4, 8);
        float sc = p * SCORE_SCALE;
        float mn = fmaxf(m, sc);
        float f = __expf(m - mn), w = __expf(sc - mn);
        l = l * f + w;
        a0 = a0 * f + w * bf2f(vw & 0xffffu);
        a1 = a1 * f + w * bf2f(vw >> 16);
        m = mn;
    }

    float inv = (l > 0.f) ? 1.f / l : 0.f;
    float2 fv = *(const float2*)(feat + (size_t)node * DIM + 2 * lane);
    float x0 = a0 * inv + fv.x;
    float x1 = a1 * inv + fv.y;

    float s1 = x0 + x1;
    float s2 = x0 * x0 + x1 * x1;
#pragma unroll
    for (int off = 1; off < 64; off <<= 1) {
        s1 += __shfl_xor(s1, off, 64);
        s2 += __shfl_xor(s2, off, 64);
    }
    float mean = s1 * (1.f / DIM);
    float var = s2 * (1.f / DIM) - mean * mean;
    float rinv = rsqrtf(var + LN_EPS);
    float g0 = g[2 * lane], g1 = g[2 * lane + 1];
    float b0 = b[2 * lane], b1 = b[2 * lane + 1];
    float o0 = (x0 - mean) * rinv * g0 + b0;
    float o1 = (x1 - mean) * rinv * g1 + b1;
    *(float2*)(rstf + (size_t)node * DIM + 2 * lane) = make_float2(o0, o1);
    unsigned int packed = (unsigned int)f2bf(o0) | ((unsigned int)f2bf(o1) << 16);
    ((unsigned int*)rstb)[(size_t)node * 64 + lane] = packed;
}

// ---------------- final residual + LN2 ----------------
__global__ __launch_bounds__(256) void ln2_kernel(
        const float* __restrict__ ffn, const float* __restrict__ rst,
        const float* __restrict__ g, const float* __restrict__ b,
        float* __restrict__ out, int n) {
    int node = blockIdx.x * 4 + (threadIdx.x >> 6);
    int lane = threadIdx.x & 63;
    if (node >= n) return;
    float2 a = *(const float2*)(ffn + (size_t)node * DIM + 2 * lane);
    float2 r = *(const float2*)(rst + (size_t)node * DIM + 2 * lane);
    float x0 = a.x + r.x;
    float x1 = a.y + r.y;
    float s1 = x0 + x1;
    float s2 = x0 * x0 + x1 * x1;
#pragma unroll
    for (int off = 1; off < 64; off <<= 1) {
        s1 += __shfl_xor(s1, off, 64);
        s2 += __shfl_xor(s2, off, 64);
    }
    float mean = s1 * (1.f / DIM);
    float var = s2 * (1.f / DIM) - mean * mean;
    float rinv = rsqrtf(var + LN_EPS);
    float g0 = g[2 * lane], g1 = g[2 * lane + 1];
    float b0 = b[2 * lane], b1 = b[2 * lane + 1];
    float2 o;
    o.x = (x0 - mean) * rinv * g0 + b0;
    o.y = (x1 - mean) * rinv * g1 + b1;
    *(float2*)(out + (size_t)node * DIM + 2 * lane) = o;
}

// ---------------- launch ----------------

extern "C" void kernel_launch(void* const* d_in, const int* in_sizes, int n_in,
                              void* d_out, int out_size, void* d_ws, size_t ws_size,
                              hipStream_t stream) {
    const float* feat   = (const float*)d_in[0];
    const int*   src    = (const int*)d_in[1];
    const int*   dst    = (const int*)d_in[2];
    const float* Wq     = (const float*)d_in[3];
    const float* Wk     = (const float*)d_in[4];
    const float* Wv     = (const float*)d_in[5];
    const float* ln1_g  = (const float*)d_in[6];
    const float* ln1_b  = (const float*)d_in[7];
    const float* ln2_g  = (const float*)d_in[8];
    const float* ln2_b  = (const float*)d_in[9];
    const float* W1     = (const float*)d_in[10];
    const float* b1     = (const float*)d_in[11];
    const float* prelu  = (const float*)d_in[12];
    const float* W2     = (const float*)d_in[13];
    const float* b2     = (const float*)d_in[14];
    float* out = (float*)d_out;

    const int Nn = in_sizes[0] / DIM;        // 40000
    const int E  = in_sizes[1];              // 640000
    const int MP = (Nn + 127) & ~127;        // 40064 — padded row count for 128-tiles

    // workspace layout (all node buffers padded to MP rows; garbage rows are
    // computed+stored by GEMMs but never consumed for real outputs)
    char* w = (char*)d_ws;
    float* rstf = (float*)w;                    w += (size_t)MP * DIM * 4;
    unsigned short* rstb = (unsigned short*)w;  w += (size_t)MP * DIM * 2;
    unsigned short* featb = (unsigned short*)w; w += (size_t)MP * DIM * 2;
    unsigned short* qkv = (unsigned short*)w;   // union with hid
    unsigned short* hid = (unsigned short*)w;   w += (size_t)MP * HID * 2;
    float* ffn = (float*)w;                     w += (size_t)MP * DIM * 4;
    unsigned short* Wqkv_t = (unsigned short*)w; w += 3 * DIM * DIM * 2;
    unsigned short* W1_t = (unsigned short*)w;   w += HID * DIM * 2;
    unsigned short* W2_t = (unsigned short*)w;   w += DIM * HID * 2;
    int* counts  = (int*)w;  w += (size_t)Nn * 4;
    int* offsets = (int*)w;  w += (size_t)(Nn + 1) * 4;
    int* srcs    = (int*)w;

    // 1. CSR build (srcs sorted by dst)
    zero_counts_kernel<<<(Nn + 255) / 256, 256, 0, stream>>>(counts, Nn);
    count_kernel<<<(E + 255) / 256, 256, 0, stream>>>(dst, counts, E);
    scan_kernel<<<1, 1024, 0, stream>>>(counts, offsets, Nn);
    fill_kernel<<<(E + 255) / 256, 256, 0, stream>>>(dst, src, counts, srcs, E);

    // 2. converts
    cvt_bf16_kernel<<<((Nn * DIM / 4) + 255) / 256, 256, 0, stream>>>(feat, featb, Nn * DIM / 4);
    transpose_cvt_kernel<<<(DIM * DIM + 255) / 256, 256, 0, stream>>>(Wq, Wqkv_t, DIM, DIM);
    transpose_cvt_kernel<<<(DIM * DIM + 255) / 256, 256, 0, stream>>>(Wk, Wqkv_t + DIM * DIM, DIM, DIM);
    transpose_cvt_kernel<<<(DIM * DIM + 255) / 256, 256, 0, stream>>>(Wv, Wqkv_t + 2 * DIM * DIM, DIM, DIM);
    transpose_cvt_kernel<<<(DIM * HID + 255) / 256, 256, 0, stream>>>(W1, W1_t, DIM, HID);
    transpose_cvt_kernel<<<(HID * DIM + 255) / 256, 256, 0, stream>>>(W2, W2_t, HID, DIM);

    // 3. fused qkv projection: [MP,128] @ [128,384] -> bf16 qkv
    {
        dim3 grid(3 * DIM / 128, MP / 128);
        mfma_gemm128<true><<<grid, 256, 0, stream>>>(featb, Wqkv_t, qkv, 3 * DIM, DIM,
                                                     nullptr, nullptr);
    }

    // 4. fused attention + residual + LN1 -> rstf (fp32) + rstb (bf16)
    agg_ln1_kernel<<<(Nn + 3) / 4, 256, 0, stream>>>(qkv, feat, srcs, offsets,
                                                     ln1_g, ln1_b, rstf, rstb, Nn);

    // 5. FFN1: rstb @ W1 + b1, PReLU -> hid (bf16; overwrites dead qkv region)
    {
        dim3 grid(HID / 128, MP / 128);
        mfma_gemm128<true><<<grid, 256, 0, stream>>>(rstb, W1_t, hid, HID, DIM, b1, prelu);
    }

    // 6. FFN2: hid @ W2 + b2 -> ffn (fp32)
    {
        dim3 grid(DIM / 128, MP / 128);
        mfma_gemm128<false><<<grid, 256, 0, stream>>>(hid, W2_t, ffn, DIM, HID, b2, nullptr);
    }

    // 7. LN2(rstf + ffn) -> out
    ln2_kernel<<<(Nn + 3) / 4, 256, 0, stream>>>(ffn, rstf, ln2_g, ln2_b, out, Nn);
}

// Round 4
// 270.383 us; speedup vs baseline: 2.4281x; 1.2218x over previous
//
#include <hip/hip_runtime.h>
#include <hip/hip_bf16.h>
#include <math.h>

#define DIM 128
#define NHEAD 8
#define DHEAD 16
#define HID 512
#define LN_EPS 1e-5f
#define SCORE_SCALE 0.08838834764831845f  // 1/sqrt(128)

typedef __bf16 bf16x8 __attribute__((ext_vector_type(8)));
typedef float f32x4 __attribute__((ext_vector_type(4)));

__device__ inline float bf2f(unsigned int bits16) {
    return __uint_as_float(bits16 << 16);
}
__device__ inline unsigned short f2bf(float f) {
    unsigned int u = __float_as_uint(f);
    unsigned int r = u + 0x7fff + ((u >> 16) & 1);   // RNE (non-NaN inputs)
    return (unsigned short)(r >> 16);
}

// async global->LDS, 16B per lane; LDS dest = wave-uniform base + lane*16
__device__ inline void gload_lds16(const void* g, void* l) {
    __builtin_amdgcn_global_load_lds(
        (const __attribute__((address_space(1))) unsigned int*)g,
        (__attribute__((address_space(3))) unsigned int*)l, 16, 0, 0);
}

// ---------------- fused prep: zero counts + feat->bf16 + weight transposes ----------------
// block ranges: [0,zb) zero | [zb,fb) featb | then Wq,Wk,Wv (64 blk each) | W1 (256) | W2 (256)
__global__ __launch_bounds__(256) void prep_kernel(
        int* counts, int Nn,
        const float* __restrict__ feat, unsigned short* __restrict__ featb,
        const float* __restrict__ Wq, const float* __restrict__ Wk, const float* __restrict__ Wv,
        unsigned short* __restrict__ Wqkvt,
        const float* __restrict__ W1, unsigned short* __restrict__ W1t,
        const float* __restrict__ W2, unsigned short* __restrict__ W2t,
        int zb, int fb) {
    int blk = blockIdx.x, t = threadIdx.x;
    if (blk < zb) {                       // zero counts: 1024 ints/block
        int i = blk * 1024 + t * 4;
        if (i < Nn) *(int4*)(counts + i) = make_int4(0, 0, 0, 0);
    } else if (blk < fb) {                // featb: 1 float4 -> 4 bf16 per thread
        int i = (blk - zb) * 256 + t;     // quad index
        if (i < Nn * 32) {
            float4 v = *(const float4*)(feat + (size_t)i * 4);
            ushort4 o;
            o.x = f2bf(v.x); o.y = f2bf(v.y); o.z = f2bf(v.z); o.w = f2bf(v.w);
            *(ushort4*)(featb + (size_t)i * 4) = o;
        }
    } else {
        int b2_ = blk - fb;
        if (b2_ < 192) {                  // Wq/Wk/Wv transpose: [128][128] -> [128][128]^T
            int sec = b2_ >> 6;           // 0,1,2
            const float* W = sec == 0 ? Wq : (sec == 1 ? Wk : Wv);
            int o = (b2_ & 63) * 256 + t; // out index in [0,16384)
            int oc = o >> 7, orow = o & 127;
            Wqkvt[sec * 16384 + o] = f2bf(W[(size_t)orow * 128 + oc]);
        } else if (b2_ < 448) {           // W1 [128][512] -> W1t [512][128]
            int o = (b2_ - 192) * 256 + t;
            int oc = o >> 7, orow = o & 127;
            W1t[o] = f2bf(W1[(size_t)orow * 512 + oc]);
        } else {                          // W2 [512][128] -> W2t [128][512]
            int o = (b2_ - 448) * 256 + t;
            int oc = o >> 9, orow = o & 511;
            W2t[o] = f2bf(W2[(size_t)orow * 128 + oc]);
        }
    }
}

// ---------------- CSR build ----------------

__global__ void count_kernel(const int* __restrict__ dst, int* counts, int E) {
    int e = blockIdx.x * blockDim.x + threadIdx.x;
    if (e < E) atomicAdd(&counts[dst[e]], 1);
}

// phase A: per-1024-chunk sums
__global__ __launch_bounds__(256) void scanA_kernel(const int* __restrict__ counts, int* bsum, int Nn) {
    int blk = blockIdx.x, t = threadIdx.x;
    int i = blk * 1024 + t * 4;
    int s = 0;
    if (i < Nn) { int4 x = *(const int4*)(counts + i); s = x.x + x.y + x.z + x.w; }
#pragma unroll
    for (int off = 1; off < 64; off <<= 1) s += __shfl_xor(s, off, 64);
    __shared__ int wt[4];
    if ((t & 63) == 0) wt[t >> 6] = s;
    __syncthreads();
    if (t == 0) bsum[blk] = wt[0] + wt[1] + wt[2] + wt[3];
}

// phase B: 1 block, exclusive scan of chunk sums (nch <= 64)
__global__ void scanB_kernel(const int* __restrict__ bsum, int* bbase, int* offsets, int nch, int Nn) {
    int t = threadIdx.x;  // 64 threads
    int v = (t < nch) ? bsum[t] : 0;
    int s = v;
#pragma unroll
    for (int off = 1; off < 64; off <<= 1) {
        int u = __shfl_up(s, off, 64);
        if (t >= off) s += u;
    }
    if (t < nch) bbase[t] = s - v;
    if (t == 63) offsets[Nn] = s;
}

// phase C: per-chunk exclusive scan + base; writes offsets and cursor (counts)
__global__ __launch_bounds__(256) void scanC_kernel(int* counts, const int* __restrict__ bbase,
                                                    int* offsets, int Nn) {
    int blk = blockIdx.x, t = threadIdx.x, lane = t & 63, wv = t >> 6;
    int i = blk * 1024 + t * 4;
    int4 x = make_int4(0, 0, 0, 0);
    if (i < Nn) x = *(const int4*)(counts + i);
    int ts = x.x + x.y + x.z + x.w;
    int s = ts;
#pragma unroll
    for (int off = 1; off < 64; off <<= 1) {
        int u = __shfl_up(s, off, 64);
        if (lane >= off) s += u;
    }
    __shared__ int wt[4];
    if (lane == 63) wt[wv] = s;
    __syncthreads();
    int woff = 0;
    for (int wi = 0; wi < wv; ++wi) woff += wt[wi];
    int excl = bbase[blk] + woff + (s - ts);
    if (i < Nn) {
        int o0 = excl, o1 = o0 + x.x, o2 = o1 + x.y, o3 = o2 + x.z;
        *(int4*)(offsets + i) = make_int4(o0, o1, o2, o3);
        *(int4*)(counts + i) = make_int4(o0, o1, o2, o3);
    }
}

__global__ void fill_kernel(const int* __restrict__ dst, const int* __restrict__ src,
                            int* cursor, int* srcs, int E) {
    int e = blockIdx.x * blockDim.x + threadIdx.x;
    if (e < E) {
        int pos = atomicAdd(&cursor[dst[e]], 1);
        srcs[pos] = src[e];
    }
}

// ---------------- qkv GEMM: [MP,128] @ [128,384] -> qb [MP][128], kv interleaved ----------------
// grid (3, MP/128): blockIdx.x = region 0:q 1:k 2:v. m97-style 128x128 tile, K=128.
__global__ __launch_bounds__(256) void qkv_gemm(
        const unsigned short* __restrict__ A, const unsigned short* __restrict__ Bt,
        unsigned short* __restrict__ qb, unsigned short* __restrict__ kv) {
    __shared__ unsigned short As[128 * 32];
    __shared__ unsigned short Bs[128 * 32];
    int t = threadIdx.x;
    int wave = t >> 6, lane = t & 63;
    int wr = wave >> 1, wc = wave & 1;
    int lrow = lane & 15, kq = lane >> 4;
    int m0 = blockIdx.y * 128;
    int region = blockIdx.x;
    int n0 = region * 128;
    int srow = t >> 2, scol8 = (t & 3) * 8;

    f32x4 acc[4][4] = {};
    for (int k0 = 0; k0 < 128; k0 += 32) {
        gload_lds16(A + (size_t)(m0 + srow) * 128 + k0 + scol8,      As + t * 8);
        gload_lds16(A + (size_t)(m0 + 64 + srow) * 128 + k0 + scol8, As + 2048 + t * 8);
        gload_lds16(Bt + (size_t)(n0 + srow) * 128 + k0 + scol8,      Bs + t * 8);
        gload_lds16(Bt + (size_t)(n0 + 64 + srow) * 128 + k0 + scol8, Bs + 2048 + t * 8);
        __syncthreads();
        bf16x8 af[4], bfr[4];
#pragma unroll
        for (int mi = 0; mi < 4; ++mi)
            af[mi] = *(const bf16x8*)(&As[(wr * 64 + mi * 16 + lrow) * 32 + kq * 8]);
#pragma unroll
        for (int ni = 0; ni < 4; ++ni)
            bfr[ni] = *(const bf16x8*)(&Bs[(wc * 64 + ni * 16 + lrow) * 32 + kq * 8]);
#pragma unroll
        for (int mi = 0; mi < 4; ++mi)
#pragma unroll
            for (int ni = 0; ni < 4; ++ni)
                acc[mi][ni] = __builtin_amdgcn_mfma_f32_16x16x32_bf16(af[mi], bfr[ni], acc[mi][ni], 0, 0, 0);
        __syncthreads();
    }
#pragma unroll
    for (int ni = 0; ni < 4; ++ni) {
        int j = wc * 64 + ni * 16 + lrow;   // col within region, 0..127
#pragma unroll
        for (int mi = 0; mi < 4; ++mi) {
#pragma unroll
            for (int r = 0; r < 4; ++r) {
                int row = m0 + wr * 64 + mi * 16 + kq * 4 + r;
                unsigned short h = f2bf(acc[mi][ni][r]);
                if (region == 0)
                    qb[(size_t)row * 128 + j] = h;
                else
                    kv[(size_t)row * 256 + (j >> 1) * 4 + (region == 2 ? 2 : 0) + (j & 1)] = h;
            }
        }
    }
}

// ---------------- fused attention aggregate + residual + LN1 ----------------
// one wave per node; q from qb, k+v from interleaved kv (one dwordx2 per edge per lane)
__global__ __launch_bounds__(256) void agg_ln1_kernel(
        const unsigned short* __restrict__ qb, const unsigned short* __restrict__ kv,
        const float* __restrict__ feat,
        const int* __restrict__ srcs, const int* __restrict__ offsets,
        const float* __restrict__ g, const float* __restrict__ b,
        float* __restrict__ rstf, unsigned short* __restrict__ rstb, int n) {
    int node = blockIdx.x * 4 + (threadIdx.x >> 6);
    int lane = threadIdx.x & 63;
    if (node >= n) return;

    unsigned int qw = ((const unsigned int*)qb)[(size_t)node * 64 + lane];
    float q0 = bf2f(qw & 0xffffu), q1 = bf2f(qw >> 16);
    const uint2* kvw = (const uint2*)kv;   // node stride 64 uint2

    int beg = offsets[node], end = offsets[node + 1];
    float m = -INFINITY, l = 0.f, a0 = 0.f, a1 = 0.f;

    int idx = beg;
    for (; idx + 8 <= end; idx += 8) {
        int s[8];
#pragma unroll
        for (int i = 0; i < 8; ++i) s[i] = srcs[idx + i];
        uint2 kvp[8];
#pragma unroll
        for (int i = 0; i < 8; ++i) kvp[i] = kvw[(size_t)s[i] * 64 + lane];
        float sc[8];
#pragma unroll
        for (int i = 0; i < 8; ++i) {
            float p = bf2f(kvp[i].x & 0xffffu) * q0 + bf2f(kvp[i].x >> 16) * q1;
            p += __shfl_xor(p, 1, 8);
            p += __shfl_xor(p, 2, 8);
            p += __shfl_xor(p, 4, 8);
            sc[i] = p * SCORE_SCALE;
        }
        float mn = m;
#pragma unroll
        for (int i = 0; i < 8; ++i) mn = fmaxf(mn, sc[i]);
        float f = __expf(m - mn);
        float wsum = 0.f, d0 = 0.f, d1 = 0.f;
#pragma unroll
        for (int i = 0; i < 8; ++i) {
            float w = __expf(sc[i] - mn);
            wsum += w;
            d0 += w * bf2f(kvp[i].y & 0xffffu);
            d1 += w * bf2f(kvp[i].y >> 16);
        }
        l = l * f + wsum;
        a0 = a0 * f + d0;
        a1 = a1 * f + d1;
        m = mn;
    }
    for (; idx < end; ++idx) {
        int s = srcs[idx];
        uint2 kvp = kvw[(size_t)s * 64 + lane];
        float p = bf2f(kvp.x & 0xffffu) * q0 + bf2f(kvp.x >> 16) * q1;
        p += __shfl_xor(p, 1, 8);
        p += __shfl_xor(p, 2, 8);
        p += __shfl_xor(p, 4, 8);
        float sc = p * SCORE_SCALE;
        float mn = fmaxf(m, sc);
        float f = __expf(m - mn), w = __expf(sc - mn);
        l = l * f + w;
        a0 = a0 * f + w * bf2f(kvp.y & 0xffffu);
        a1 = a1 * f + w * bf2f(kvp.y >> 16);
        m = mn;
    }

    float inv = (l > 0.f) ? 1.f / l : 0.f;
    float2 fv = *(const float2*)(feat + (size_t)node * DIM + 2 * lane);
    float x0 = a0 * inv + fv.x;
    float x1 = a1 * inv + fv.y;

    float s1 = x0 + x1;
    float s2 = x0 * x0 + x1 * x1;
#pragma unroll
    for (int off = 1; off < 64; off <<= 1) {
        s1 += __shfl_xor(s1, off, 64);
        s2 += __shfl_xor(s2, off, 64);
    }
    float mean = s1 * (1.f / DIM);
    float var = s2 * (1.f / DIM) - mean * mean;
    float rinv = rsqrtf(var + LN_EPS);
    float g0 = g[2 * lane], g1 = g[2 * lane + 1];
    float b0 = b[2 * lane], b1 = b[2 * lane + 1];
    float o0 = (x0 - mean) * rinv * g0 + b0;
    float o1 = (x1 - mean) * rinv * g1 + b1;
    *(float2*)(rstf + (size_t)node * DIM + 2 * lane) = make_float2(o0, o1);
    unsigned int packed = (unsigned int)f2bf(o0) | ((unsigned int)f2bf(o1) << 16);
    ((unsigned int*)rstb)[(size_t)node * 64 + lane] = packed;
}

// ---------------- fused FFN: PReLU(rst@W1+b1)@W2 + b2 + rst, then LN2 -> out ----------------
// per 128-row block: rst tile resident in LDS; 4 hidden chunks of 128:
//   GEMM1 (hiddenxnode via swapped operands) -> Hs (LDS, A-operand layout) -> GEMM2 accumulate.
#define FST 136   // padded LDS row stride in shorts (16B-aligned, +8 pad)
__global__ __launch_bounds__(256, 2) void ffn_fused_kernel(
        const unsigned short* __restrict__ rstb, const float* __restrict__ rstf,
        const unsigned short* __restrict__ W1t, const float* __restrict__ b1,
        const float* __restrict__ prelu,
        const unsigned short* __restrict__ W2t, const float* __restrict__ b2,
        const float* __restrict__ g, const float* __restrict__ bb,
        float* __restrict__ out, int Nn) {
    __shared__ unsigned short As[128 * FST];
    __shared__ unsigned short Hs[128 * FST];
    __shared__ unsigned short Bs[128 * 32];
    __shared__ float red[128][4];

    int t = threadIdx.x, wave = t >> 6, lane = t & 63;
    int lrow = lane & 15, kq = lane >> 4;
    int wr = wave >> 1, wc = wave & 1;
    int m0 = blockIdx.x * 128;
    int srow = t >> 2, scol8 = (t & 3) * 8;

    // stage rst tile (bf16) into padded As via VGPR round-trip (one-time)
    {
        int row = t >> 1, half = t & 1;
        const float4* src = (const float4*)(rstb + (size_t)(m0 + row) * 128 + half * 64);
        float4* dst = (float4*)(As + row * FST + half * 64);
#pragma unroll
        for (int i = 0; i < 8; ++i) dst[i] = src[i];
    }
    f32x4 facc[4][4] = {};
    __syncthreads();

    for (int c = 0; c < 4; ++c) {
        // ---- GEMM1: H_c[hidden 128][node 128] = W1_c @ rst^T (swapped operands) ----
        f32x4 hacc[4][4] = {};
        for (int k0 = 0; k0 < 128; k0 += 32) {
            gload_lds16(W1t + (size_t)(c * 128 + srow) * 128 + k0 + scol8,      Bs + t * 8);
            gload_lds16(W1t + (size_t)(c * 128 + 64 + srow) * 128 + k0 + scol8, Bs + 2048 + t * 8);
            __syncthreads();
            bf16x8 hf[4], nf[4];
#pragma unroll
            for (int hi = 0; hi < 4; ++hi)
                hf[hi] = *(const bf16x8*)(&Bs[(wr * 64 + hi * 16 + lrow) * 32 + kq * 8]);
#pragma unroll
            for (int nj = 0; nj < 4; ++nj)
                nf[nj] = *(const bf16x8*)(&As[(wc * 64 + nj * 16 + lrow) * FST + k0 + kq * 8]);
#pragma unroll
            for (int hi = 0; hi < 4; ++hi)
#pragma unroll
                for (int nj = 0; nj < 4; ++nj)
                    hacc[hi][nj] = __builtin_amdgcn_mfma_f32_16x16x32_bf16(hf[hi], nf[nj], hacc[hi][nj], 0, 0, 0);
            __syncthreads();
        }
        // epilogue GEMM1: bias + PReLU, write Hs[node][hidloc] (bf16)
#pragma unroll
        for (int hi = 0; hi < 4; ++hi) {
            int hloc = wr * 64 + hi * 16 + kq * 4;   // + r
#pragma unroll
            for (int r = 0; r < 4; ++r) {
                int hg = c * 128 + hloc + r;
                float biv = b1[hg], pwv = prelu[hg];
#pragma unroll
                for (int nj = 0; nj < 4; ++nj) {
                    int node = wc * 64 + nj * 16 + lrow;
                    float v = hacc[hi][nj][r] + biv;
                    v = v >= 0.f ? v : pwv * v;
                    Hs[node * FST + hloc + r] = f2bf(v);
                }
            }
        }
        __syncthreads();
        // ---- GEMM2: facc[node 128][out 128] += Hs @ W2_c ----
        for (int k0 = 0; k0 < 128; k0 += 32) {
            gload_lds16(W2t + (size_t)srow * 512 + c * 128 + k0 + scol8,        Bs + t * 8);
            gload_lds16(W2t + (size_t)(64 + srow) * 512 + c * 128 + k0 + scol8, Bs + 2048 + t * 8);
            __syncthreads();
            bf16x8 af[4], bf2r[4];
#pragma unroll
            for (int mi = 0; mi < 4; ++mi)
                af[mi] = *(const bf16x8*)(&Hs[(wr * 64 + mi * 16 + lrow) * FST + k0 + kq * 8]);
#pragma unroll
            for (int ni = 0; ni < 4; ++ni)
                bf2r[ni] = *(const bf16x8*)(&Bs[(wc * 64 + ni * 16 + lrow) * 32 + kq * 8]);
#pragma unroll
            for (int mi = 0; mi < 4; ++mi)
#pragma unroll
                for (int ni = 0; ni < 4; ++ni)
                    facc[mi][ni] = __builtin_amdgcn_mfma_f32_16x16x32_bf16(af[mi], bf2r[ni], facc[mi][ni], 0, 0, 0);
            __syncthreads();
        }
    }

    // ---- epilogue: + b2 + residual, LN2, store ----
    float b2v[4], gv[4], bv[4];
    int cols[4];
#pragma unroll
    for (int ni = 0; ni < 4; ++ni) {
        cols[ni] = wc * 64 + ni * 16 + lrow;
        b2v[ni] = b2[cols[ni]]; gv[ni] = g[cols[ni]]; bv[ni] = bb[cols[ni]];
    }
#pragma unroll
    for (int mi = 0; mi < 4; ++mi) {
#pragma unroll
        for (int r = 0; r < 4; ++r) {
            int rloc = wr * 64 + mi * 16 + kq * 4 + r;
            int row = m0 + rloc;
            float ps = 0.f, pq = 0.f;
#pragma unroll
            for (int ni = 0; ni < 4; ++ni) {
                float v = facc[mi][ni][r] + b2v[ni] + rstf[(size_t)row * 128 + cols[ni]];
                facc[mi][ni][r] = v;
                ps += v; pq += v * v;
            }
#pragma unroll
            for (int off = 1; off < 16; off <<= 1) {
                ps += __shfl_xor(ps, off, 16);
                pq += __shfl_xor(pq, off, 16);
            }
            if (lrow == 0) { red[rloc][wc * 2] = ps; red[rloc][wc * 2 + 1] = pq; }
        }
    }
    __syncthreads();
#pragma unroll
    for (int mi = 0; mi < 4; ++mi) {
#pragma unroll
        for (int r = 0; r < 4; ++r) {
            int rloc = wr * 64 + mi * 16 + kq * 4 + r;
            int row = m0 + rloc;
            float s1 = red[rloc][0] + red[rloc][2];
            float s2 = red[rloc][1] + red[rloc][3];
            float mean = s1 * (1.f / DIM);
            float var = s2 * (1.f / DIM) - mean * mean;
            float rs = rsqrtf(var + LN_EPS);
            if (row < Nn) {
#pragma unroll
                for (int ni = 0; ni < 4; ++ni)
                    out[(size_t)row * 128 + cols[ni]] =
                        (facc[mi][ni][r] - mean) * rs * gv[ni] + bv[ni];
            }
        }
    }
}

// ---------------- launch ----------------

extern "C" void kernel_launch(void* const* d_in, const int* in_sizes, int n_in,
                              void* d_out, int out_size, void* d_ws, size_t ws_size,
                              hipStream_t stream) {
    const float* feat   = (const float*)d_in[0];
    const int*   src    = (const int*)d_in[1];
    const int*   dst    = (const int*)d_in[2];
    const float* Wq     = (const float*)d_in[3];
    const float* Wk     = (const float*)d_in[4];
    const float* Wv     = (const float*)d_in[5];
    const float* ln1_g  = (const float*)d_in[6];
    const float* ln1_b  = (const float*)d_in[7];
    const float* ln2_g  = (const float*)d_in[8];
    const float* ln2_b  = (const float*)d_in[9];
    const float* W1     = (const float*)d_in[10];
    const float* b1     = (const float*)d_in[11];
    const float* prelu  = (const float*)d_in[12];
    const float* W2     = (const float*)d_in[13];
    const float* b2     = (const float*)d_in[14];
    float* out = (float*)d_out;

    const int Nn = in_sizes[0] / DIM;        // 40000
    const int E  = in_sizes[1];              // 640000
    const int MP = (Nn + 127) & ~127;        // 40064

    char* w = (char*)d_ws;
    unsigned short* qb   = (unsigned short*)w; w += (size_t)MP * DIM * 2;
    unsigned short* kv   = (unsigned short*)w; w += (size_t)MP * 256 * 2;
    float* rstf          = (float*)w;          w += (size_t)MP * DIM * 4;
    unsigned short* rstb = (unsigned short*)w; w += (size_t)MP * DIM * 2;
    unsigned short* featb= (unsigned short*)w; w += (size_t)MP * DIM * 2;
    unsigned short* Wqkvt= (unsigned short*)w; w += 3 * DIM * DIM * 2;
    unsigned short* W1t  = (unsigned short*)w; w += (size_t)HID * DIM * 2;
    unsigned short* W2t  = (unsigned short*)w; w += (size_t)DIM * HID * 2;
    int* counts  = (int*)w;  w += (size_t)Nn * 4;
    int* offsets = (int*)w;  w += (size_t)(Nn + 4) * 4;
    int* bsum    = (int*)w;  w += 64 * 4;
    int* bbase   = (int*)w;  w += 64 * 4;
    int* srcs    = (int*)w;

    const int NCH = (Nn + 1023) / 1024;      // 40
    const int zb = NCH;
    const int fb = zb + Nn / 8;              // featb blocks: Nn*32 quads / 256

    // 1. prep (zero counts, feat cvt, weight transposes)
    prep_kernel<<<fb + 192 + 256 + 256, 256, 0, stream>>>(
        counts, Nn, feat, featb, Wq, Wk, Wv, Wqkvt, W1, W1t, W2, W2t, zb, fb);

    // 2. CSR build
    count_kernel<<<(E + 255) / 256, 256, 0, stream>>>(dst, counts, E);
    scanA_kernel<<<NCH, 256, 0, stream>>>(counts, bsum, Nn);
    scanB_kernel<<<1, 64, 0, stream>>>(bsum, bbase, offsets, NCH, Nn);
    scanC_kernel<<<NCH, 256, 0, stream>>>(counts, bbase, offsets, Nn);
    fill_kernel<<<(E + 255) / 256, 256, 0, stream>>>(dst, src, counts, srcs, E);

    // 3. qkv projection -> qb + interleaved kv
    {
        dim3 grid(3, MP / 128);
        qkv_gemm<<<grid, 256, 0, stream>>>(featb, Wqkvt, qb, kv);
    }

    // 4. fused attention + residual + LN1
    agg_ln1_kernel<<<(Nn + 3) / 4, 256, 0, stream>>>(qb, kv, feat, srcs, offsets,
                                                     ln1_g, ln1_b, rstf, rstb, Nn);

    // 5. fused FFN + residual + LN2 -> out
    ffn_fused_kernel<<<MP / 128, 256, 0, stream>>>(rstb, rstf, W1t, b1, prelu,
                                                   W2t, b2, ln2_g, ln2_b, out, Nn);
}

// Round 5
// 262.644 us; speedup vs baseline: 2.4997x; 1.0295x over previous
//
#include <hip/hip_runtime.h>
#include <hip/hip_bf16.h>
#include <math.h>

#define DIM 128
#define NHEAD 8
#define DHEAD 16
#define HID 512
#define LN_EPS 1e-5f
// score = (k·q)/sqrt(128); we fold (1/sqrt(128))*log2(e) into q so softmax runs in exp2 domain
#define QSCALE 0.12751879104863297f   // 0.08838834764831845 * 1.4426950408889634

typedef __bf16 bf16x8 __attribute__((ext_vector_type(8)));
typedef float f32x4 __attribute__((ext_vector_type(4)));
typedef _Float16 f16x2 __attribute__((ext_vector_type(2)));

__device__ inline float bf2f(unsigned int bits16) {
    return __uint_as_float(bits16 << 16);
}
__device__ inline unsigned short f2bf(float f) {
    unsigned int u = __float_as_uint(f);
    unsigned int r = u + 0x7fff + ((u >> 16) & 1);   // RNE
    return (unsigned short)(r >> 16);
}
__device__ inline unsigned short f2h(float f) {
    _Float16 h = (_Float16)f;
    return __builtin_bit_cast(unsigned short, h);
}
__device__ inline float edot2(unsigned int kw, f16x2 q) {
#if __has_builtin(__builtin_amdgcn_fdot2)
    return __builtin_amdgcn_fdot2(__builtin_bit_cast(f16x2, kw), q, 0.f, false);
#else
    f16x2 k = __builtin_bit_cast(f16x2, kw);
    return (float)k.x * (float)q.x + (float)k.y * (float)q.y;
#endif
}
__device__ inline float fexp2(float x) {
#if __has_builtin(__builtin_amdgcn_exp2f)
    return __builtin_amdgcn_exp2f(x);
#else
    return exp2f(x);
#endif
}

// async global->LDS, 16B per lane
__device__ inline void gload_lds16(const void* g, void* l) {
    __builtin_amdgcn_global_load_lds(
        (const __attribute__((address_space(1))) unsigned int*)g,
        (__attribute__((address_space(3))) unsigned int*)l, 16, 0, 0);
}

// ---------------- fused prep: zero counts + feat->bf16 + weight transposes ----------------
__global__ __launch_bounds__(256) void prep_kernel(
        int* counts, int Nn,
        const float* __restrict__ feat, unsigned short* __restrict__ featb,
        const float* __restrict__ Wq, const float* __restrict__ Wk, const float* __restrict__ Wv,
        unsigned short* __restrict__ Wqkvt,
        const float* __restrict__ W1, unsigned short* __restrict__ W1t,
        const float* __restrict__ W2, unsigned short* __restrict__ W2t,
        int zb, int fb) {
    int blk = blockIdx.x, t = threadIdx.x;
    if (blk < zb) {
        int i = blk * 1024 + t * 4;
        if (i < Nn) *(int4*)(counts + i) = make_int4(0, 0, 0, 0);
    } else if (blk < fb) {
        int i = (blk - zb) * 256 + t;
        if (i < Nn * 32) {
            float4 v = *(const float4*)(feat + (size_t)i * 4);
            ushort4 o;
            o.x = f2bf(v.x); o.y = f2bf(v.y); o.z = f2bf(v.z); o.w = f2bf(v.w);
            *(ushort4*)(featb + (size_t)i * 4) = o;
        }
    } else {
        int b2_ = blk - fb;
        if (b2_ < 192) {
            int sec = b2_ >> 6;
            const float* W = sec == 0 ? Wq : (sec == 1 ? Wk : Wv);
            int o = (b2_ & 63) * 256 + t;
            int oc = o >> 7, orow = o & 127;
            Wqkvt[sec * 16384 + o] = f2bf(W[(size_t)orow * 128 + oc]);
        } else if (b2_ < 448) {
            int o = (b2_ - 192) * 256 + t;
            int oc = o >> 7, orow = o & 127;
            W1t[o] = f2bf(W1[(size_t)orow * 512 + oc]);
        } else {
            int o = (b2_ - 448) * 256 + t;
            int oc = o >> 9, orow = o & 511;
            W2t[o] = f2bf(W2[(size_t)orow * 128 + oc]);
        }
    }
}

// ---------------- CSR build ----------------

__global__ void count_kernel(const int* __restrict__ dst, int* counts, int E) {
    int e = blockIdx.x * blockDim.x + threadIdx.x;
    if (e < E) atomicAdd(&counts[dst[e]], 1);
}

__global__ __launch_bounds__(256) void scanA_kernel(const int* __restrict__ counts, int* bsum, int Nn) {
    int blk = blockIdx.x, t = threadIdx.x;
    int i = blk * 1024 + t * 4;
    int s = 0;
    if (i < Nn) { int4 x = *(const int4*)(counts + i); s = x.x + x.y + x.z + x.w; }
#pragma unroll
    for (int off = 1; off < 64; off <<= 1) s += __shfl_xor(s, off, 64);
    __shared__ int wt[4];
    if ((t & 63) == 0) wt[t >> 6] = s;
    __syncthreads();
    if (t == 0) bsum[blk] = wt[0] + wt[1] + wt[2] + wt[3];
}

// per-chunk scan with inline chunk-base scan (NCH <= 64); writes offsets + cursor
__global__ __launch_bounds__(256) void scanC_kernel(int* counts, const int* __restrict__ bsum,
                                                    int* offsets, int Nn, int NCH) {
    int blk = blockIdx.x, t = threadIdx.x, lane = t & 63, wv = t >> 6;
    __shared__ int wt[4];
    __shared__ int base_s;
    if (wv == 0) {
        int v = (lane < NCH) ? bsum[lane] : 0;
        int s = v;
#pragma unroll
        for (int off = 1; off < 64; off <<= 1) {
            int u = __shfl_up(s, off, 64);
            if (lane >= off) s += u;
        }
        int basev = (blk > 0) ? __shfl(s, blk - 1, 64) : 0;
        int tot = __shfl(s, NCH - 1, 64);
        if (lane == 0) {
            base_s = basev;
            if (blk == 0) offsets[Nn] = tot;
        }
    }
    int i = blk * 1024 + t * 4;
    int4 x = make_int4(0, 0, 0, 0);
    if (i < Nn) x = *(const int4*)(counts + i);
    int ts = x.x + x.y + x.z + x.w;
    int s = ts;
#pragma unroll
    for (int off = 1; off < 64; off <<= 1) {
        int u = __shfl_up(s, off, 64);
        if (lane >= off) s += u;
    }
    if (lane == 63) wt[wv] = s;
    __syncthreads();
    int woff = 0;
    for (int wi = 0; wi < wv; ++wi) woff += wt[wi];
    int excl = base_s + woff + (s - ts);
    if (i < Nn) {
        int o0 = excl, o1 = o0 + x.x, o2 = o1 + x.y, o3 = o2 + x.z;
        *(int4*)(offsets + i) = make_int4(o0, o1, o2, o3);
        *(int4*)(counts + i) = make_int4(o0, o1, o2, o3);
    }
}

__global__ void fill_kernel(const int* __restrict__ dst, const int* __restrict__ src,
                            int* cursor, int* srcs, int E) {
    int e = blockIdx.x * blockDim.x + threadIdx.x;
    if (e < E) {
        int pos = atomicAdd(&cursor[dst[e]], 1);
        srcs[pos] = src[e];
    }
}

// ---------------- qkv GEMM -> f16 q (pre-scaled), f16 k, f16 v ----------------
// grid (3, MP/128): blockIdx.x = region 0:q 1:k 2:v. Epilogue stages tile in LDS,
// then fully-coalesced 16B stores (each [128][128] f16 tile is contiguous in global).
#define QST 136   // LDS stage row stride (shorts), 16B-aligned with +8 pad
__global__ __launch_bounds__(256) void qkv_gemm(
        const unsigned short* __restrict__ A, const unsigned short* __restrict__ Bt,
        unsigned short* __restrict__ qb, unsigned short* __restrict__ kb,
        unsigned short* __restrict__ vb) {
    __shared__ unsigned short smem[128 * QST];   // stage; first 16KB doubles as As|Bs
    unsigned short* As = smem;
    unsigned short* Bs = smem + 4096;
    int t = threadIdx.x;
    int wave = t >> 6, lane = t & 63;
    int wr = wave >> 1, wc = wave & 1;
    int lrow = lane & 15, kq = lane >> 4;
    int m0 = blockIdx.y * 128;
    int region = blockIdx.x;
    int n0 = region * 128;
    int srow = t >> 2, scol8 = (t & 3) * 8;

    f32x4 acc[4][4] = {};
    for (int k0 = 0; k0 < 128; k0 += 32) {
        gload_lds16(A + (size_t)(m0 + srow) * 128 + k0 + scol8,      As + t * 8);
        gload_lds16(A + (size_t)(m0 + 64 + srow) * 128 + k0 + scol8, As + 2048 + t * 8);
        gload_lds16(Bt + (size_t)(n0 + srow) * 128 + k0 + scol8,      Bs + t * 8);
        gload_lds16(Bt + (size_t)(n0 + 64 + srow) * 128 + k0 + scol8, Bs + 2048 + t * 8);
        __syncthreads();
        bf16x8 af[4], bfr[4];
#pragma unroll
        for (int mi = 0; mi < 4; ++mi)
            af[mi] = *(const bf16x8*)(&As[(wr * 64 + mi * 16 + lrow) * 32 + kq * 8]);
#pragma unroll
        for (int ni = 0; ni < 4; ++ni)
            bfr[ni] = *(const bf16x8*)(&Bs[(wc * 64 + ni * 16 + lrow) * 32 + kq * 8]);
#pragma unroll
        for (int mi = 0; mi < 4; ++mi)
#pragma unroll
            for (int ni = 0; ni < 4; ++ni)
                acc[mi][ni] = __builtin_amdgcn_mfma_f32_16x16x32_bf16(af[mi], bfr[ni], acc[mi][ni], 0, 0, 0);
        __syncthreads();
    }

    float scale = (region == 0) ? QSCALE : 1.f;
#pragma unroll
    for (int ni = 0; ni < 4; ++ni) {
        int col = wc * 64 + ni * 16 + lrow;
#pragma unroll
        for (int mi = 0; mi < 4; ++mi) {
#pragma unroll
            for (int r = 0; r < 4; ++r) {
                int row = wr * 64 + mi * 16 + kq * 4 + r;
                smem[row * QST + col] = f2h(acc[mi][ni][r] * scale);
            }
        }
    }
    __syncthreads();
    unsigned short* outp = (region == 0 ? qb : (region == 1 ? kb : vb)) + (size_t)m0 * 128;
#pragma unroll
    for (int i = 0; i < 8; ++i) {
        int chunk = i * 256 + t;            // 16B chunk id, 2048 total
        int row = chunk >> 4, c16 = chunk & 15;
        *(float4*)(outp + (size_t)chunk * 8) = *(const float4*)(smem + row * QST + c16 * 8);
    }
}

// ---------------- fused attention aggregate + residual + LN1 ----------------
// one wave per node, 2 dims/lane; f16 q/k/v, fdot2 scores (log2 domain), exp2 softmax
__global__ __launch_bounds__(256) void agg_ln1_kernel(
        const unsigned short* __restrict__ qb, const unsigned short* __restrict__ kb,
        const unsigned short* __restrict__ vb,
        const float* __restrict__ feat,
        const int* __restrict__ srcs, const int* __restrict__ offsets,
        const float* __restrict__ g, const float* __restrict__ b,
        unsigned short* __restrict__ rstb, int n) {
    int node = blockIdx.x * 4 + (threadIdx.x >> 6);
    int lane = threadIdx.x & 63;
    if (node >= n) return;

    const unsigned int* q32 = (const unsigned int*)qb;
    const unsigned int* k32 = (const unsigned int*)kb;
    const unsigned int* v32 = (const unsigned int*)vb;
    f16x2 qp = __builtin_bit_cast(f16x2, q32[(size_t)node * 64 + lane]);

    int beg = offsets[node], end = offsets[node + 1];
    float m = -INFINITY, l = 0.f, a0 = 0.f, a1 = 0.f;

    int idx = beg;
    for (; idx + 8 <= end; idx += 8) {
        int s[8];
#pragma unroll
        for (int i = 0; i < 8; ++i) s[i] = srcs[idx + i];
        unsigned int kw[8], vw[8];
#pragma unroll
        for (int i = 0; i < 8; ++i) kw[i] = k32[(size_t)s[i] * 64 + lane];
#pragma unroll
        for (int i = 0; i < 8; ++i) vw[i] = v32[(size_t)s[i] * 64 + lane];
        float sc[8];
#pragma unroll
        for (int i = 0; i < 8; ++i) {
            float p = edot2(kw[i], qp);
            p += __shfl_xor(p, 1, 8);
            p += __shfl_xor(p, 2, 8);
            p += __shfl_xor(p, 4, 8);
            sc[i] = p;
        }
        float mn = m;
#pragma unroll
        for (int i = 0; i < 8; ++i) mn = fmaxf(mn, sc[i]);
        float f = fexp2(m - mn);
        float wsum = 0.f, d0 = 0.f, d1 = 0.f;
#pragma unroll
        for (int i = 0; i < 8; ++i) {
            float w = fexp2(sc[i] - mn);
            f16x2 vp = __builtin_bit_cast(f16x2, vw[i]);
            wsum += w;
            d0 = fmaf((float)vp.x, w, d0);
            d1 = fmaf((float)vp.y, w, d1);
        }
        l = l * f + wsum;
        a0 = a0 * f + d0;
        a1 = a1 * f + d1;
        m = mn;
    }
    for (; idx < end; ++idx) {
        int s = srcs[idx];
        unsigned int kw = k32[(size_t)s * 64 + lane];
        unsigned int vw = v32[(size_t)s * 64 + lane];
        float p = edot2(kw, qp);
        p += __shfl_xor(p, 1, 8);
        p += __shfl_xor(p, 2, 8);
        p += __shfl_xor(p, 4, 8);
        float mn = fmaxf(m, p);
        float f = fexp2(m - mn), w = fexp2(p - mn);
        f16x2 vp = __builtin_bit_cast(f16x2, vw);
        l = l * f + w;
        a0 = a0 * f + w * (float)vp.x;
        a1 = a1 * f + w * (float)vp.y;
        m = mn;
    }

    float inv = (l > 0.f) ? 1.f / l : 0.f;
    float2 fv = *(const float2*)(feat + (size_t)node * DIM + 2 * lane);
    float x0 = a0 * inv + fv.x;
    float x1 = a1 * inv + fv.y;

    float s1 = x0 + x1;
    float s2 = x0 * x0 + x1 * x1;
#pragma unroll
    for (int off = 1; off < 64; off <<= 1) {
        s1 += __shfl_xor(s1, off, 64);
        s2 += __shfl_xor(s2, off, 64);
    }
    float mean = s1 * (1.f / DIM);
    float var = s2 * (1.f / DIM) - mean * mean;
    float rinv = rsqrtf(var + LN_EPS);
    float g0 = g[2 * lane], g1 = g[2 * lane + 1];
    float b0 = b[2 * lane], b1 = b[2 * lane + 1];
    float o0 = (x0 - mean) * rinv * g0 + b0;
    float o1 = (x1 - mean) * rinv * g1 + b1;
    unsigned int packed = (unsigned int)f2bf(o0) | ((unsigned int)f2bf(o1) << 16);
    ((unsigned int*)rstb)[(size_t)node * 64 + lane] = packed;
}

// ---------------- fused FFN + residual + LN2 ----------------
#define FST 136
__global__ __launch_bounds__(256, 2) void ffn_fused_kernel(
        const unsigned short* __restrict__ rstb,
        const unsigned short* __restrict__ W1t, const float* __restrict__ b1,
        const float* __restrict__ prelu,
        const unsigned short* __restrict__ W2t, const float* __restrict__ b2,
        const float* __restrict__ g, const float* __restrict__ bb,
        float* __restrict__ out, int Nn) {
    __shared__ unsigned short As[128 * FST];
    __shared__ unsigned short Hs[128 * FST];
    __shared__ unsigned short Bs[128 * 32];
    __shared__ float red[128][4];

    int t = threadIdx.x, wave = t >> 6, lane = t & 63;
    int lrow = lane & 15, kq = lane >> 4;
    int wr = wave >> 1, wc = wave & 1;
    int m0 = blockIdx.x * 128;
    int srow = t >> 2, scol8 = (t & 3) * 8;

    {
        int row = t >> 1, half = t & 1;
        const float4* src = (const float4*)(rstb + (size_t)(m0 + row) * 128 + half * 64);
        float4* dst = (float4*)(As + row * FST + half * 64);
#pragma unroll
        for (int i = 0; i < 8; ++i) dst[i] = src[i];
    }
    f32x4 facc[4][4] = {};
    __syncthreads();

    for (int c = 0; c < 4; ++c) {
        f32x4 hacc[4][4] = {};
        for (int k0 = 0; k0 < 128; k0 += 32) {
            gload_lds16(W1t + (size_t)(c * 128 + srow) * 128 + k0 + scol8,      Bs + t * 8);
            gload_lds16(W1t + (size_t)(c * 128 + 64 + srow) * 128 + k0 + scol8, Bs + 2048 + t * 8);
            __syncthreads();
            bf16x8 hf[4], nf[4];
#pragma unroll
            for (int hi = 0; hi < 4; ++hi)
                hf[hi] = *(const bf16x8*)(&Bs[(wr * 64 + hi * 16 + lrow) * 32 + kq * 8]);
#pragma unroll
            for (int nj = 0; nj < 4; ++nj)
                nf[nj] = *(const bf16x8*)(&As[(wc * 64 + nj * 16 + lrow) * FST + k0 + kq * 8]);
#pragma unroll
            for (int hi = 0; hi < 4; ++hi)
#pragma unroll
                for (int nj = 0; nj < 4; ++nj)
                    hacc[hi][nj] = __builtin_amdgcn_mfma_f32_16x16x32_bf16(hf[hi], nf[nj], hacc[hi][nj], 0, 0, 0);
            __syncthreads();
        }
#pragma unroll
        for (int hi = 0; hi < 4; ++hi) {
            int hloc = wr * 64 + hi * 16 + kq * 4;
#pragma unroll
            for (int r = 0; r < 4; ++r) {
                int hg = c * 128 + hloc + r;
                float biv = b1[hg], pwv = prelu[hg];
#pragma unroll
                for (int nj = 0; nj < 4; ++nj) {
                    int node = wc * 64 + nj * 16 + lrow;
                    float v = hacc[hi][nj][r] + biv;
                    v = v >= 0.f ? v : pwv * v;
                    Hs[node * FST + hloc + r] = f2bf(v);
                }
            }
        }
        __syncthreads();
        for (int k0 = 0; k0 < 128; k0 += 32) {
            gload_lds16(W2t + (size_t)srow * 512 + c * 128 + k0 + scol8,        Bs + t * 8);
            gload_lds16(W2t + (size_t)(64 + srow) * 512 + c * 128 + k0 + scol8, Bs + 2048 + t * 8);
            __syncthreads();
            bf16x8 af[4], bf2r[4];
#pragma unroll
            for (int mi = 0; mi < 4; ++mi)
                af[mi] = *(const bf16x8*)(&Hs[(wr * 64 + mi * 16 + lrow) * FST + k0 + kq * 8]);
#pragma unroll
            for (int ni = 0; ni < 4; ++ni)
                bf2r[ni] = *(const bf16x8*)(&Bs[(wc * 64 + ni * 16 + lrow) * 32 + kq * 8]);
#pragma unroll
            for (int mi = 0; mi < 4; ++mi)
#pragma unroll
                for (int ni = 0; ni < 4; ++ni)
                    facc[mi][ni] = __builtin_amdgcn_mfma_f32_16x16x32_bf16(af[mi], bf2r[ni], facc[mi][ni], 0, 0, 0);
            __syncthreads();
        }
    }

    float b2v[4], gv[4], bv[4];
    int cols[4];
#pragma unroll
    for (int ni = 0; ni < 4; ++ni) {
        cols[ni] = wc * 64 + ni * 16 + lrow;
        b2v[ni] = b2[cols[ni]]; gv[ni] = g[cols[ni]]; bv[ni] = bb[cols[ni]];
    }
#pragma unroll
    for (int mi = 0; mi < 4; ++mi) {
#pragma unroll
        for (int r = 0; r < 4; ++r) {
            int rloc = wr * 64 + mi * 16 + kq * 4 + r;
            int row = m0 + rloc;
            float ps = 0.f, pq = 0.f;
#pragma unroll
            for (int ni = 0; ni < 4; ++ni) {
                float rsv = bf2f(rstb[(size_t)row * 128 + cols[ni]]);
                float v = facc[mi][ni][r] + b2v[ni] + rsv;
                facc[mi][ni][r] = v;
                ps += v; pq += v * v;
            }
#pragma unroll
            for (int off = 1; off < 16; off <<= 1) {
                ps += __shfl_xor(ps, off, 16);
                pq += __shfl_xor(pq, off, 16);
            }
            if (lrow == 0) { red[rloc][wc * 2] = ps; red[rloc][wc * 2 + 1] = pq; }
        }
    }
    __syncthreads();
#pragma unroll
    for (int mi = 0; mi < 4; ++mi) {
#pragma unroll
        for (int r = 0; r < 4; ++r) {
            int rloc = wr * 64 + mi * 16 + kq * 4 + r;
            int row = m0 + rloc;
            float s1 = red[rloc][0] + red[rloc][2];
            float s2 = red[rloc][1] + red[rloc][3];
            float mean = s1 * (1.f / DIM);
            float var = s2 * (1.f / DIM) - mean * mean;
            float rs = rsqrtf(var + LN_EPS);
            if (row < Nn) {
#pragma unroll
                for (int ni = 0; ni < 4; ++ni)
                    out[(size_t)row * 128 + cols[ni]] =
                        (facc[mi][ni][r] - mean) * rs * gv[ni] + bv[ni];
            }
        }
    }
}

// ---------------- launch ----------------

extern "C" void kernel_launch(void* const* d_in, const int* in_sizes, int n_in,
                              void* d_out, int out_size, void* d_ws, size_t ws_size,
                              hipStream_t stream) {
    const float* feat   = (const float*)d_in[0];
    const int*   src    = (const int*)d_in[1];
    const int*   dst    = (const int*)d_in[2];
    const float* Wq     = (const float*)d_in[3];
    const float* Wk     = (const float*)d_in[4];
    const float* Wv     = (const float*)d_in[5];
    const float* ln1_g  = (const float*)d_in[6];
    const float* ln1_b  = (const float*)d_in[7];
    const float* ln2_g  = (const float*)d_in[8];
    const float* ln2_b  = (const float*)d_in[9];
    const float* W1     = (const float*)d_in[10];
    const float* b1     = (const float*)d_in[11];
    const float* prelu  = (const float*)d_in[12];
    const float* W2     = (const float*)d_in[13];
    const float* b2     = (const float*)d_in[14];
    float* out = (float*)d_out;

    const int Nn = in_sizes[0] / DIM;        // 40000
    const int E  = in_sizes[1];              // 640000
    const int MP = (Nn + 127) & ~127;        // 40064

    char* w = (char*)d_ws;
    unsigned short* qb   = (unsigned short*)w; w += (size_t)MP * DIM * 2;
    unsigned short* kb   = (unsigned short*)w; w += (size_t)MP * DIM * 2;
    unsigned short* vb   = (unsigned short*)w; w += (size_t)MP * DIM * 2;
    unsigned short* rstb = (unsigned short*)w; w += (size_t)MP * DIM * 2;
    unsigned short* featb= (unsigned short*)w; w += (size_t)MP * DIM * 2;
    unsigned short* Wqkvt= (unsigned short*)w; w += 3 * DIM * DIM * 2;
    unsigned short* W1t  = (unsigned short*)w; w += (size_t)HID * DIM * 2;
    unsigned short* W2t  = (unsigned short*)w; w += (size_t)DIM * HID * 2;
    int* counts  = (int*)w;  w += (size_t)Nn * 4;
    int* offsets = (int*)w;  w += (size_t)(Nn + 4) * 4;
    int* bsum    = (int*)w;  w += 64 * 4;
    int* srcs    = (int*)w;

    const int NCH = (Nn + 1023) / 1024;      // 40 (must be <= 64)
    const int zb = NCH;
    const int fb = zb + Nn / 8;

    prep_kernel<<<fb + 192 + 256 + 256, 256, 0, stream>>>(
        counts, Nn, feat, featb, Wq, Wk, Wv, Wqkvt, W1, W1t, W2, W2t, zb, fb);

    count_kernel<<<(E + 255) / 256, 256, 0, stream>>>(dst, counts, E);
    scanA_kernel<<<NCH, 256, 0, stream>>>(counts, bsum, Nn);
    scanC_kernel<<<NCH, 256, 0, stream>>>(counts, bsum, offsets, Nn, NCH);
    fill_kernel<<<(E + 255) / 256, 256, 0, stream>>>(dst, src, counts, srcs, E);

    {
        dim3 grid(3, MP / 128);
        qkv_gemm<<<grid, 256, 0, stream>>>(featb, Wqkvt, qb, kb, vb);
    }

    agg_ln1_kernel<<<(Nn + 3) / 4, 256, 0, stream>>>(qb, kb, vb, feat, srcs, offsets,
                                                     ln1_g, ln1_b, rstb, Nn);

    ffn_fused_kernel<<<MP / 128, 256, 0, stream>>>(rstb, W1t, b1, prelu,
                                                   W2t, b2, ln2_g, ln2_b, out, Nn);
}